// Round 1
// baseline (1449.924 us; speedup 1.0000x reference)
//
#include <hip/hip_runtime.h>

// Hierarchical (3-level pooled) multi-head attention, fp32 baseline.
// B=2, S=2048, D=1024, H=16, DH=64, LEVELS=3, FACTOR=2.
//
// Pipeline:
//   1. gemm_f32<1>: qh/kh0/vh0 = X@W + b, stored head-major [B,H,S,DH]
//      (pooling commutes with the linear projection, so K/V are projected once)
//   2. pool2: kh1,kh2,vh1,vh2 by pair-mean along S
//   3. attn_f32: flash attention per (b,h,qtile), all 3 levels accumulated
//      with weight w_l/sum(w) into acc [B,S,D]
//   4. gemm_f32<0>: out = acc@Wo + bo   (bias algebra folds exactly)

#define B_  2
#define S_  2048
#define D_  1024
#define H_  16
#define DH_ 64

// ---------------- fp32 GEMM: C[M,N] = A[M,K]@B[K,N] + bias ----------------
// MODE 0: row-major store. MODE 1: head-major permuted store [B,H,S,DH].
template<int MODE>
__global__ __launch_bounds__(256) void gemm_f32(
    const float* __restrict__ A, const float* __restrict__ Bw,
    const float* __restrict__ bias, float* __restrict__ C,
    int M, int N, int Kd)
{
    __shared__ __align__(16) float As[16][132];  // As[k][m] (transposed), pad 132 keeps 16B align + spreads banks
    __shared__ __align__(16) float Bs[16][132];  // Bs[k][n]
    const int t  = threadIdx.x;
    const int ty = t >> 4, tx = t & 15;
    const int br = blockIdx.y * 128, bc = blockIdx.x * 128;

    float acc[8][8];
    #pragma unroll
    for (int i = 0; i < 8; ++i)
        #pragma unroll
        for (int j = 0; j < 8; ++j) acc[i][j] = 0.f;

    for (int kt = 0; kt < Kd; kt += 16) {
        #pragma unroll
        for (int rr = 0; rr < 2; ++rr) {
            // A tile 128x16 -> transposed scatter
            int r  = (t >> 2) + rr * 64;
            int k4 = (t & 3) * 4;
            float4 a4 = *(const float4*)&A[(size_t)(br + r) * Kd + kt + k4];
            As[k4+0][r] = a4.x; As[k4+1][r] = a4.y;
            As[k4+2][r] = a4.z; As[k4+3][r] = a4.w;
            // B tile 16x128 -> direct copy
            int kk = (t >> 5) + rr * 8;
            int n4 = (t & 31) * 4;
            *(float4*)&Bs[kk][n4] = *(const float4*)&Bw[(size_t)(kt + kk) * N + bc + n4];
        }
        __syncthreads();
        #pragma unroll
        for (int k = 0; k < 16; ++k) {
            float a0[4], a1[4], b0[4], b1[4];
            *(float4*)a0 = *(const float4*)&As[k][ty*4];
            *(float4*)a1 = *(const float4*)&As[k][64 + ty*4];
            *(float4*)b0 = *(const float4*)&Bs[k][tx*4];
            *(float4*)b1 = *(const float4*)&Bs[k][64 + tx*4];
            #pragma unroll
            for (int i = 0; i < 4; ++i) {
                #pragma unroll
                for (int j = 0; j < 4; ++j) {
                    acc[i][j]     = fmaf(a0[i], b0[j], acc[i][j]);
                    acc[i][j+4]   = fmaf(a0[i], b1[j], acc[i][j+4]);
                    acc[i+4][j]   = fmaf(a1[i], b0[j], acc[i+4][j]);
                    acc[i+4][j+4] = fmaf(a1[i], b1[j], acc[i+4][j+4]);
                }
            }
        }
        __syncthreads();
    }

    #pragma unroll
    for (int jq = 0; jq < 2; ++jq) {
        int cbase = bc + jq*64 + tx*4;
        float4 bv4 = *(const float4*)&bias[cbase];
        #pragma unroll
        for (int iq = 0; iq < 2; ++iq) {
            #pragma unroll
            for (int i = 0; i < 4; ++i) {
                int r = br + iq*64 + ty*4 + i;
                float4 v4;
                v4.x = acc[iq*4+i][jq*4+0] + bv4.x;
                v4.y = acc[iq*4+i][jq*4+1] + bv4.y;
                v4.z = acc[iq*4+i][jq*4+2] + bv4.z;
                v4.w = acc[iq*4+i][jq*4+3] + bv4.w;
                if (MODE == 0) {
                    *(float4*)&C[(size_t)r * N + cbase] = v4;
                } else {
                    int bI = r >> 11, sI = r & (S_ - 1);
                    int hI = cbase >> 6, dhI = cbase & (DH_ - 1);
                    *(float4*)&C[(((size_t)(bI*H_ + hI))*S_ + sI)*DH_ + dhI] = v4;
                }
            }
        }
    }
}

// ---------------- pair mean-pool along S, layout [B*H][S][DH] ----------------
__global__ __launch_bounds__(256) void pool2(
    const float* __restrict__ in, float* __restrict__ out, int nOut, int Sin)
{
    int idx = blockIdx.x * 256 + threadIdx.x;
    if (idx >= nOut) return;
    int d    = idx & (DH_ - 1);
    int rest = idx >> 6;
    int Sout = Sin >> 1;
    int so = rest % Sout;
    int bh = rest / Sout;
    size_t base = ((size_t)bh * Sin + 2 * so) * DH_ + d;
    out[idx] = 0.5f * (in[base] + in[base + DH_]);
}

// ---------------- flash attention, 3 levels fused ----------------
// block = (b,h,qtile of 64 rows), 256 threads as 16x16 (ty=row group, tx=col group)
__global__ __launch_bounds__(256) void attn_f32(
    const float* __restrict__ qh,
    const float* __restrict__ kh0, const float* __restrict__ kh1, const float* __restrict__ kh2,
    const float* __restrict__ vh0, const float* __restrict__ vh1, const float* __restrict__ vh2,
    const float* __restrict__ wlv, float* __restrict__ accOut)
{
    __shared__ __align__(16) float qs[64][68];  // [d][i] transposed (pre-scaled by 1/8)
    __shared__ __align__(16) float ks[64][68];  // [d][j] transposed
    __shared__ __align__(16) float vs[64][68];  // [j][d] row-major
    __shared__ __align__(16) float ps[64][68];  // [j][i] transposed

    const int t   = threadIdx.x;
    const int ty  = t >> 4, tx = t & 15;
    const int bid = blockIdx.x;
    const int qt  = bid & 31;
    const int h   = (bid >> 5) & (H_ - 1);
    const int b   = bid >> 9;

    const float w0 = wlv[0], w1 = wlv[1], w2 = wlv[2];
    const float winv = 1.f / (w0 + w1 + w2);

    {   // stage Q tile (once), transposed + pre-scaled
        const float* qb = qh + (((size_t)(b*H_ + h))*S_ + qt*64) * DH_;
        #pragma unroll
        for (int rr = 0; rr < 4; ++rr) {
            int u  = t + 256*rr;
            int i  = u >> 4;
            int d0 = (u & 15) * 4;
            float4 v4 = *(const float4*)&qb[(size_t)i*DH_ + d0];
            qs[d0+0][i] = v4.x * 0.125f;
            qs[d0+1][i] = v4.y * 0.125f;
            qs[d0+2][i] = v4.z * 0.125f;
            qs[d0+3][i] = v4.w * 0.125f;
        }
    }

    float accO[4][4];
    #pragma unroll
    for (int i = 0; i < 4; ++i)
        #pragma unroll
        for (int j = 0; j < 4; ++j) accO[i][j] = 0.f;

    #pragma unroll 1
    for (int lvl = 0; lvl < 3; ++lvl) {
        const float* kb; const float* vb; int ntiles; float wcur;
        if (lvl == 0)      { kb = kh0; vb = vh0; ntiles = 32; wcur = w0; }
        else if (lvl == 1) { kb = kh1; vb = vh1; ntiles = 16; wcur = w1; }
        else               { kb = kh2; vb = vh2; ntiles = 8;  wcur = w2; }
        size_t hb = (size_t)(b*H_ + h) * ((size_t)ntiles*64) * DH_;
        kb += hb; vb += hb;

        float m_i[4], l_i[4], o[4][4];
        #pragma unroll
        for (int i = 0; i < 4; ++i) {
            m_i[i] = -1e30f; l_i[i] = 0.f;
            #pragma unroll
            for (int j = 0; j < 4; ++j) o[i][j] = 0.f;
        }

        for (int kt = 0; kt < ntiles; ++kt) {
            __syncthreads();   // prev tile's PV reads of ks/vs/ps done
            #pragma unroll
            for (int rr = 0; rr < 4; ++rr) {
                int u  = t + 256*rr;
                int j  = u >> 4;
                int d0 = (u & 15) * 4;
                float4 k4 = *(const float4*)&kb[(size_t)(kt*64 + j)*DH_ + d0];
                ks[d0+0][j] = k4.x; ks[d0+1][j] = k4.y;
                ks[d0+2][j] = k4.z; ks[d0+3][j] = k4.w;
                float4 v4 = *(const float4*)&vb[(size_t)(kt*64 + j)*DH_ + d0];
                *(float4*)&vs[j][d0] = v4;
            }
            __syncthreads();

            // ---- QK^T (already scaled via qs) ----
            float s[4][4];
            #pragma unroll
            for (int i = 0; i < 4; ++i)
                #pragma unroll
                for (int j = 0; j < 4; ++j) s[i][j] = 0.f;
            #pragma unroll 4
            for (int d = 0; d < 64; ++d) {
                float a[4], kk[4];
                *(float4*)a  = *(const float4*)&qs[d][ty*4];
                *(float4*)kk = *(const float4*)&ks[d][tx*4];
                #pragma unroll
                for (int i = 0; i < 4; ++i)
                    #pragma unroll
                    for (int j = 0; j < 4; ++j)
                        s[i][j] = fmaf(a[i], kk[j], s[i][j]);
            }

            // ---- online softmax ----
            float pmax[4];
            #pragma unroll
            for (int i = 0; i < 4; ++i)
                pmax[i] = fmaxf(fmaxf(s[i][0], s[i][1]), fmaxf(s[i][2], s[i][3]));
            #pragma unroll
            for (int off = 1; off < 16; off <<= 1)
                #pragma unroll
                for (int i = 0; i < 4; ++i)
                    pmax[i] = fmaxf(pmax[i], __shfl_xor(pmax[i], off, 64));

            float mnew[4], corr[4], rsum[4], p[4][4];
            #pragma unroll
            for (int i = 0; i < 4; ++i) {
                mnew[i] = fmaxf(m_i[i], pmax[i]);
                corr[i] = __expf(m_i[i] - mnew[i]);
                float r = 0.f;
                #pragma unroll
                for (int j = 0; j < 4; ++j) { p[i][j] = __expf(s[i][j] - mnew[i]); r += p[i][j]; }
                rsum[i] = r;
            }
            #pragma unroll
            for (int off = 1; off < 16; off <<= 1)
                #pragma unroll
                for (int i = 0; i < 4; ++i)
                    rsum[i] += __shfl_xor(rsum[i], off, 64);
            #pragma unroll
            for (int i = 0; i < 4; ++i) {
                l_i[i] = l_i[i]*corr[i] + rsum[i];
                m_i[i] = mnew[i];
                #pragma unroll
                for (int j = 0; j < 4; ++j) o[i][j] *= corr[i];
            }

            // write P transposed: ps[col j][row i]
            #pragma unroll
            for (int j = 0; j < 4; ++j) {
                float4 col = make_float4(p[0][j], p[1][j], p[2][j], p[3][j]);
                *(float4*)&ps[tx*4 + j][ty*4] = col;
            }
            __syncthreads();

            // ---- O += P @ V ----
            #pragma unroll 4
            for (int j = 0; j < 64; ++j) {
                float pi[4], vv[4];
                *(float4*)pi = *(const float4*)&ps[j][ty*4];
                *(float4*)vv = *(const float4*)&vs[j][tx*4];
                #pragma unroll
                for (int i = 0; i < 4; ++i)
                    #pragma unroll
                    for (int jj = 0; jj < 4; ++jj)
                        o[i][jj] = fmaf(pi[i], vv[jj], o[i][jj]);
            }
        }

        float wl_ = wcur * winv;
        #pragma unroll
        for (int i = 0; i < 4; ++i) {
            float sc = wl_ / l_i[i];
            #pragma unroll
            for (int j = 0; j < 4; ++j) accO[i][j] += o[i][j] * sc;
        }
    }

    #pragma unroll
    for (int i = 0; i < 4; ++i) {
        size_t r = (size_t)b*S_ + qt*64 + ty*4 + i;
        float4 v4 = make_float4(accO[i][0], accO[i][1], accO[i][2], accO[i][3]);
        *(float4*)&accOut[r*D_ + h*DH_ + tx*4] = v4;
    }
}

// ---------------- launch ----------------
extern "C" void kernel_launch(void* const* d_in, const int* in_sizes, int n_in,
                              void* d_out, int out_size, void* d_ws, size_t ws_size,
                              hipStream_t stream)
{
    const float* query = (const float*)d_in[0];
    const float* key   = (const float*)d_in[1];
    const float* value = (const float*)d_in[2];
    const float* Wq = (const float*)d_in[3];  const float* bq = (const float*)d_in[4];
    const float* Wk = (const float*)d_in[5];  const float* bk = (const float*)d_in[6];
    const float* Wv = (const float*)d_in[7];  const float* bv = (const float*)d_in[8];
    const float* Wo = (const float*)d_in[9];  const float* bo = (const float*)d_in[10];
    const float* wlv = (const float*)d_in[11];

    float* ws  = (float*)d_ws;
    float* qh  = ws;                 // 4194304  [B,H,S,DH]
    float* kh0 = qh  + 4194304;      // 4194304
    float* kh1 = kh0 + 4194304;      // 2097152
    float* kh2 = kh1 + 2097152;      // 1048576
    float* vh0 = kh2 + 1048576;      // 4194304
    float* vh1 = vh0 + 4194304;      // 2097152
    float* vh2 = vh1 + 2097152;      // 1048576
    float* acc = vh2 + 1048576;      // 4194304  [B,S,D]
    float* outp = (float*)d_out;

    const int M = B_ * S_;           // 4096
    dim3 gg(D_ / 128, M / 128), bb(256);

    gemm_f32<1><<<gg, bb, 0, stream>>>(query, Wq, bq, qh,  M, D_, D_);
    gemm_f32<1><<<gg, bb, 0, stream>>>(key,   Wk, bk, kh0, M, D_, D_);
    gemm_f32<1><<<gg, bb, 0, stream>>>(value, Wv, bv, vh0, M, D_, D_);

    int n1 = B_ * H_ * (S_/2) * DH_;   // 2097152
    int n2 = B_ * H_ * (S_/4) * DH_;   // 1048576
    pool2<<<(n1 + 255)/256, 256, 0, stream>>>(kh0, kh1, n1, S_);
    pool2<<<(n2 + 255)/256, 256, 0, stream>>>(kh1, kh2, n2, S_/2);
    pool2<<<(n1 + 255)/256, 256, 0, stream>>>(vh0, vh1, n1, S_);
    pool2<<<(n2 + 255)/256, 256, 0, stream>>>(vh1, vh2, n2, S_/2);

    attn_f32<<<B_ * H_ * (S_/64), bb, 0, stream>>>(qh, kh0, kh1, kh2,
                                                   vh0, vh1, vh2, wlv, acc);

    gemm_f32<0><<<gg, bb, 0, stream>>>(acc, Wo, bo, outp, M, D_, D_);
}

// Round 2
// 819.087 us; speedup vs baseline: 1.7702x; 1.7702x over previous
//
#include <hip/hip_runtime.h>

// Hierarchical 3-level pooled MHA. Round 2: attention on MFMA (bf16), fp32 GEMMs.
// B=2, S=2048, D=1024, H=16, DH=64.
//
//   1. gemm_proj<1>: qh/kh0/vh0 = (X@W + b)*scale, bf16, head-major [B,H,S,DH]
//      (Q pre-scaled by 1/sqrt(DH)=0.125 — exact power of 2)
//   2. pool2_bf16: kh1,kh2,vh1,vh2 pair-mean along S (fp32 math, bf16 storage)
//   3. attn_mfma: flash attention, mfma_f32_16x16x32_bf16, 3 levels fused,
//      fp32 accumulate -> acc [B,S,D] f32
//   4. gemm_proj<0>: out = acc@Wo + bo (fp32)

#define B_  2
#define S_  2048
#define D_  1024
#define H_  16
#define DH_ 64

typedef short s8v __attribute__((ext_vector_type(8)));   // 8 bf16 (4 VGPRs)
typedef float f4v __attribute__((ext_vector_type(4)));   // MFMA accum

__device__ __forceinline__ unsigned short f2bf(float f){
    union { float f; unsigned u; } v; v.f = f;
    unsigned r = v.u + 0x7FFFu + ((v.u >> 16) & 1u);     // RNE
    return (unsigned short)(r >> 16);
}
__device__ __forceinline__ float bf2f(unsigned short h){
    union { unsigned u; float f; } v; v.u = ((unsigned)h) << 16;
    return v.f;
}

// XOR-swizzled byte offset of the 16B block (row, kblk) in a [rows][64bf16] tile.
// Row stride 128B; swizzle spreads the 8 blocks of a row across banks so that
// fixed-kblk column reads (stride 128B) don't all hit bank 0. Same function on
// write and read sides (involution) => layout-correct by construction.
__device__ __forceinline__ int swz(int row, int kb){
    return row*128 + (((kb) ^ (row & 7) ^ ((row >> 3) & 7)) << 4);
}

// ---------------- fp32 GEMM: C = A@B + bias ----------------
// MODE 0: f32 row-major out. MODE 1: bf16 head-major out [B,H,S,DH], *scale.
template<int MODE>
__global__ __launch_bounds__(256) void gemm_proj(
    const float* __restrict__ A, const float* __restrict__ Bw,
    const float* __restrict__ bias, void* __restrict__ Cv,
    int M, int N, int Kd, float scale)
{
    __shared__ __align__(16) float As[16][132];
    __shared__ __align__(16) float Bs[16][132];
    const int t  = threadIdx.x;
    const int ty = t >> 4, tx = t & 15;
    const int br = blockIdx.y * 128, bc = blockIdx.x * 128;

    float acc[8][8];
    #pragma unroll
    for (int i = 0; i < 8; ++i)
        #pragma unroll
        for (int j = 0; j < 8; ++j) acc[i][j] = 0.f;

    for (int kt = 0; kt < Kd; kt += 16) {
        #pragma unroll
        for (int rr = 0; rr < 2; ++rr) {
            int r  = (t >> 2) + rr * 64;
            int k4 = (t & 3) * 4;
            float4 a4 = *(const float4*)&A[(size_t)(br + r) * Kd + kt + k4];
            As[k4+0][r] = a4.x; As[k4+1][r] = a4.y;
            As[k4+2][r] = a4.z; As[k4+3][r] = a4.w;
            int kk = (t >> 5) + rr * 8;
            int n4 = (t & 31) * 4;
            *(float4*)&Bs[kk][n4] = *(const float4*)&Bw[(size_t)(kt + kk) * N + bc + n4];
        }
        __syncthreads();
        #pragma unroll
        for (int k = 0; k < 16; ++k) {
            float a0[4], a1[4], b0[4], b1[4];
            *(float4*)a0 = *(const float4*)&As[k][ty*4];
            *(float4*)a1 = *(const float4*)&As[k][64 + ty*4];
            *(float4*)b0 = *(const float4*)&Bs[k][tx*4];
            *(float4*)b1 = *(const float4*)&Bs[k][64 + tx*4];
            #pragma unroll
            for (int i = 0; i < 4; ++i) {
                #pragma unroll
                for (int j = 0; j < 4; ++j) {
                    acc[i][j]     = fmaf(a0[i], b0[j], acc[i][j]);
                    acc[i][j+4]   = fmaf(a0[i], b1[j], acc[i][j+4]);
                    acc[i+4][j]   = fmaf(a1[i], b0[j], acc[i+4][j]);
                    acc[i+4][j+4] = fmaf(a1[i], b1[j], acc[i+4][j+4]);
                }
            }
        }
        __syncthreads();
    }

    #pragma unroll
    for (int jq = 0; jq < 2; ++jq) {
        int cbase = bc + jq*64 + tx*4;
        float4 bv4 = *(const float4*)&bias[cbase];
        #pragma unroll
        for (int iq = 0; iq < 2; ++iq) {
            #pragma unroll
            for (int i = 0; i < 4; ++i) {
                int r = br + iq*64 + ty*4 + i;
                float4 v4;
                v4.x = acc[iq*4+i][jq*4+0] + bv4.x;
                v4.y = acc[iq*4+i][jq*4+1] + bv4.y;
                v4.z = acc[iq*4+i][jq*4+2] + bv4.z;
                v4.w = acc[iq*4+i][jq*4+3] + bv4.w;
                if (MODE == 0) {
                    *(float4*)&((float*)Cv)[(size_t)r * N + cbase] = v4;
                } else {
                    int bI = r >> 11, sI = r & (S_ - 1);
                    int hI = cbase >> 6, dhI = cbase & (DH_ - 1);
                    ushort4 u;
                    u.x = f2bf(v4.x * scale); u.y = f2bf(v4.y * scale);
                    u.z = f2bf(v4.z * scale); u.w = f2bf(v4.w * scale);
                    *(ushort4*)&((unsigned short*)Cv)[
                        (((size_t)(bI*H_ + hI))*S_ + sI)*DH_ + dhI] = u;
                }
            }
        }
    }
}

// ---------------- pair mean-pool along S (bf16 in/out, fp32 math) ----------------
__global__ __launch_bounds__(256) void pool2_bf16(
    const unsigned short* __restrict__ in, unsigned short* __restrict__ out,
    int nOut4, int Sin)
{
    int idx = blockIdx.x * 256 + threadIdx.x;
    if (idx >= nOut4) return;
    int d0   = (idx & 15) * 4;
    int rest = idx >> 4;
    int Sout = Sin >> 1;
    int so = rest % Sout;
    int bh = rest / Sout;
    size_t base = ((size_t)bh * Sin + 2*so) * DH_ + d0;
    ushort4 a = *(const ushort4*)&in[base];
    ushort4 c = *(const ushort4*)&in[base + DH_];
    ushort4 o;
    o.x = f2bf(0.5f*(bf2f(a.x)+bf2f(c.x)));
    o.y = f2bf(0.5f*(bf2f(a.y)+bf2f(c.y)));
    o.z = f2bf(0.5f*(bf2f(a.z)+bf2f(c.z)));
    o.w = f2bf(0.5f*(bf2f(a.w)+bf2f(c.w)));
    *(ushort4*)&out[(size_t)idx*4] = o;
}

// ---------------- MFMA flash attention, 3 levels fused ----------------
// Block: 256 threads = 4 waves; wave w owns q-rows [qt*64+w*16, +16).
// Per KV tile (64 keys): stage K row-major + V transposed into swizzled LDS,
// QK^T (8 mfma/wave), online softmax (16-lane shuffles), P -> per-wave LDS,
// PV (8 mfma/wave).
__global__ __launch_bounds__(256) void attn_mfma(
    const unsigned short* __restrict__ qh,
    const unsigned short* __restrict__ kh0, const unsigned short* __restrict__ kh1,
    const unsigned short* __restrict__ kh2,
    const unsigned short* __restrict__ vh0, const unsigned short* __restrict__ vh1,
    const unsigned short* __restrict__ vh2,
    const float* __restrict__ wlv, float* __restrict__ accOut)
{
    __shared__ __align__(16) unsigned short ksm[64*64];   // K  [key][dh]  8KB
    __shared__ __align__(16) unsigned short vsm[64*64];   // V^T [dh][key] 8KB
    __shared__ __align__(16) unsigned short psm[4*16*64]; // P per wave    8KB

    const int t  = threadIdx.x;
    const int l  = t & 63, wv = t >> 6;
    const int g  = l >> 4, x = l & 15;
    const int bid = blockIdx.x;
    const int qt = bid & 31, h = (bid >> 5) & (H_-1), b = bid >> 9;

    char* ksB = (char*)ksm;
    char* vsB = (char*)vsm;
    char* psB = (char*)psm + wv*2048;

    const float w0 = wlv[0], w1 = wlv[1], w2 = wlv[2];
    const float winv = 1.f/(w0+w1+w2);

    // Q fragments in registers (A-operand: m=x, k=g*8+j per 32-chunk)
    const unsigned short* qp =
        qh + (((size_t)(b*H_+h))*S_ + (size_t)qt*64 + wv*16 + x)*DH_ + g*8;
    s8v qf0 = *(const s8v*)qp;
    s8v qf1 = *(const s8v*)(qp + 32);

    f4v accO[4];
    #pragma unroll
    for (int f = 0; f < 4; ++f) accO[f] = (f4v){0.f,0.f,0.f,0.f};

    #pragma unroll 1
    for (int lvl = 0; lvl < 3; ++lvl) {
        const unsigned short *kp, *vp; int nt; float wc;
        if (lvl == 0)      { kp = kh0; vp = vh0; nt = 32; wc = w0; }
        else if (lvl == 1) { kp = kh1; vp = vh1; nt = 16; wc = w1; }
        else               { kp = kh2; vp = vh2; nt = 8;  wc = w2; }
        size_t hb = (size_t)(b*H_+h) * (size_t)(nt*64) * DH_;
        kp += hb; vp += hb;

        float m_i[4], l_i[4];
        f4v o[4];
        #pragma unroll
        for (int r = 0; r < 4; ++r) { m_i[r] = -1e30f; l_i[r] = 0.f; }
        #pragma unroll
        for (int f = 0; f < 4; ++f) o[f] = (f4v){0.f,0.f,0.f,0.f};

        for (int kt = 0; kt < nt; ++kt) {
            __syncthreads();   // prev tile reads of ksm/vsm done
            #pragma unroll
            for (int p = 0; p < 2; ++p) {
                int lin = t + 256*p;
                int row = lin >> 3;          // key row 0..63
                int kb  = lin & 7;           // 16B block
                s8v kv = *(const s8v*)(kp + ((size_t)(kt*64+row))*DH_ + kb*8);
                *(s8v*)(ksB + swz(row, kb)) = kv;
                int d0 = kb*8;
                s8v vv = *(const s8v*)(vp + ((size_t)(kt*64+row))*DH_ + d0);
                #pragma unroll
                for (int i = 0; i < 8; ++i)  // transpose scatter: vsm[d][key]
                    *(unsigned short*)(vsB + swz(d0+i, row>>3) + ((row&7)<<1))
                        = (unsigned short)vv[i];
            }
            __syncthreads();

            // ---- S = Q@K^T (pre-scaled) ----
            f4v s[4];
            #pragma unroll
            for (int f = 0; f < 4; ++f) s[f] = (f4v){0.f,0.f,0.f,0.f};
            #pragma unroll
            for (int c = 0; c < 2; ++c) {
                s8v a = c ? qf1 : qf0;
                #pragma unroll
                for (int f = 0; f < 4; ++f) {
                    int key = f*16 + x;
                    s8v kf = *(const s8v*)(ksB + swz(key, c*4 + g));
                    s[f] = __builtin_amdgcn_mfma_f32_16x16x32_bf16(a, kf, s[f], 0,0,0);
                }
            }

            // ---- online softmax (rows r live on lanes sharing g) ----
            float pm[4];
            #pragma unroll
            for (int r = 0; r < 4; ++r)
                pm[r] = fmaxf(fmaxf(s[0][r], s[1][r]), fmaxf(s[2][r], s[3][r]));
            #pragma unroll
            for (int off = 1; off < 16; off <<= 1)
                #pragma unroll
                for (int r = 0; r < 4; ++r)
                    pm[r] = fmaxf(pm[r], __shfl_xor(pm[r], off, 64));

            float corr[4], rs[4], p[4][4];
            #pragma unroll
            for (int r = 0; r < 4; ++r) {
                float mn = fmaxf(m_i[r], pm[r]);
                corr[r] = __expf(m_i[r] - mn);
                m_i[r]  = mn;
                float a = 0.f;
                #pragma unroll
                for (int f = 0; f < 4; ++f) { p[f][r] = __expf(s[f][r] - mn); a += p[f][r]; }
                rs[r] = a;
            }
            #pragma unroll
            for (int off = 1; off < 16; off <<= 1)
                #pragma unroll
                for (int r = 0; r < 4; ++r)
                    rs[r] += __shfl_xor(rs[r], off, 64);
            #pragma unroll
            for (int r = 0; r < 4; ++r) {
                l_i[r] = l_i[r]*corr[r] + rs[r];
                #pragma unroll
                for (int f = 0; f < 4; ++f) o[f][r] *= corr[r];
            }

            // ---- P (bf16) -> per-wave LDS [q=0..15][k=0..63] ----
            #pragma unroll
            for (int f = 0; f < 4; ++f) {
                int k  = f*16 + x;
                int kb = k >> 3, kin = (k & 7) << 1;
                #pragma unroll
                for (int r = 0; r < 4; ++r) {
                    int q = g*4 + r;
                    *(unsigned short*)(psB + swz(q, kb) + kin) = f2bf(p[f][r]);
                }
            }
            // same-wave ds_write -> ds_read: DS pipe is in-order; no barrier needed

            // ---- O += P@V ----
            #pragma unroll
            for (int c = 0; c < 2; ++c) {
                s8v pa = *(const s8v*)(psB + swz(x, c*4 + g));
                #pragma unroll
                for (int f = 0; f < 4; ++f) {
                    int d = f*16 + x;
                    s8v vf = *(const s8v*)(vsB + swz(d, c*4 + g));
                    o[f] = __builtin_amdgcn_mfma_f32_16x16x32_bf16(pa, vf, o[f], 0,0,0);
                }
            }
        }

        float wl = wc * winv;
        #pragma unroll
        for (int r = 0; r < 4; ++r) {
            float sc = wl / l_i[r];
            #pragma unroll
            for (int f = 0; f < 4; ++f) accO[f][r] += o[f][r] * sc;
        }
    }

    #pragma unroll
    for (int r = 0; r < 4; ++r) {
        size_t qrow = (size_t)b*S_ + (size_t)qt*64 + wv*16 + g*4 + r;
        #pragma unroll
        for (int f = 0; f < 4; ++f)
            accOut[qrow*D_ + h*DH_ + f*16 + x] = accO[f][r];
    }
}

// ---------------- launch ----------------
extern "C" void kernel_launch(void* const* d_in, const int* in_sizes, int n_in,
                              void* d_out, int out_size, void* d_ws, size_t ws_size,
                              hipStream_t stream)
{
    const float* query = (const float*)d_in[0];
    const float* key   = (const float*)d_in[1];
    const float* value = (const float*)d_in[2];
    const float* Wq = (const float*)d_in[3];  const float* bq = (const float*)d_in[4];
    const float* Wk = (const float*)d_in[5];  const float* bk = (const float*)d_in[6];
    const float* Wv = (const float*)d_in[7];  const float* bv = (const float*)d_in[8];
    const float* Wo = (const float*)d_in[9];  const float* bo = (const float*)d_in[10];
    const float* wlv = (const float*)d_in[11];

    char* w = (char*)d_ws;
    unsigned short* qhb  = (unsigned short*)(w);             // 8,388,608 B
    unsigned short* khb0 = (unsigned short*)(w + 8388608);   // 8,388,608
    unsigned short* khb1 = (unsigned short*)(w + 16777216);  // 4,194,304
    unsigned short* khb2 = (unsigned short*)(w + 20971520);  // 2,097,152
    unsigned short* vhb0 = (unsigned short*)(w + 23068672);  // 8,388,608
    unsigned short* vhb1 = (unsigned short*)(w + 31457280);  // 4,194,304
    unsigned short* vhb2 = (unsigned short*)(w + 35651584);  // 2,097,152
    float*          accf = (float*)(w + 37748736);           // 16,777,216

    const int M = B_ * S_;
    dim3 gg(D_ / 128, M / 128), bb(256);

    gemm_proj<1><<<gg, bb, 0, stream>>>(query, Wq, bq, qhb,  M, D_, D_, 0.125f);
    gemm_proj<1><<<gg, bb, 0, stream>>>(key,   Wk, bk, khb0, M, D_, D_, 1.0f);
    gemm_proj<1><<<gg, bb, 0, stream>>>(value, Wv, bv, vhb0, M, D_, D_, 1.0f);

    int n1 = B_ * H_ * (S_/2) * DH_ / 4;   // 524288
    int n2 = B_ * H_ * (S_/4) * DH_ / 4;   // 262144
    pool2_bf16<<<n1/256, 256, 0, stream>>>(khb0, khb1, n1, S_);
    pool2_bf16<<<n2/256, 256, 0, stream>>>(khb1, khb2, n2, S_/2);
    pool2_bf16<<<n1/256, 256, 0, stream>>>(vhb0, vhb1, n1, S_);
    pool2_bf16<<<n2/256, 256, 0, stream>>>(vhb1, vhb2, n2, S_/2);

    attn_mfma<<<B_*H_*(S_/64), 256, 0, stream>>>(qhb, khb0, khb1, khb2,
                                                 vhb0, vhb1, vhb2, wlv, accf);

    gemm_proj<0><<<gg, bb, 0, stream>>>(accf, Wo, bo, d_out, M, D_, D_, 1.0f);
}

// Round 3
// 259.526 us; speedup vs baseline: 5.5868x; 3.1561x over previous
//
#include <hip/hip_runtime.h>

// Hierarchical 3-level pooled MHA. Round 3: everything on bf16 MFMA.
// B=2, S=2048, D=1024, H=16, DH=64.
//
//   0. wtrans: W[k][n] f32 -> Wt[n][k] bf16 (x4 weights, one launch)
//   1. gemm_mfma<1,1>: heads = (Xf32 @ W + b)*scale -> bf16 head-major [B,H,S,DH]
//      (A converted f32->bf16 in-register during LDS staging)
//   2. pool2_bf16: kh1,kh2,vh1,vh2 pair-mean along S
//   3. attn_mfma2: flash attention, swapped QK^T (lane-local softmax),
//      cvt_pk P-pack + vectorized P store, T14 async staging -> acc bf16 [B,S,D]
//   4. gemm_mfma<0,0>: out = acc @ Wo + bo (f32 out)

#define B_  2
#define S_  2048
#define D_  1024
#define H_  16
#define DH_ 64

typedef short s8v __attribute__((ext_vector_type(8)));   // 8 bf16
typedef float f4v __attribute__((ext_vector_type(4)));   // MFMA accum
typedef unsigned int u32x2 __attribute__((ext_vector_type(2)));

__device__ __forceinline__ unsigned cvtpk(float lo, float hi){
    unsigned r;
    asm volatile("v_cvt_pk_bf16_f32 %0, %1, %2" : "=v"(r) : "v"(lo), "v"(hi));
    return r;
}
__device__ __forceinline__ unsigned short f2bf1(float v){
    unsigned r;
    asm volatile("v_cvt_pk_bf16_f32 %0, %1, %2" : "=v"(r) : "v"(v), "v"(v));
    return (unsigned short)r;
}
__device__ __forceinline__ float bf2f(unsigned short h){
    union { unsigned u; float f; } v; v.u = ((unsigned)h) << 16;
    return v.f;
}
// XOR-swizzled byte offset of 16B block kb in row `row` of a [rows][64bf16] tile
// (128B rows). Same function on write & read sides => layout-consistent.
__device__ __forceinline__ int swz(int row, int kb){
    return row*128 + (((kb) ^ (row & 7) ^ ((row >> 3) & 7)) << 4);
}

// ---------------- W transpose + bf16 convert: Wt[n][k] = bf16(W[k][n]) ----------------
__global__ __launch_bounds__(256) void wtrans(
    const float* __restrict__ W0, const float* __restrict__ W1,
    const float* __restrict__ W2, const float* __restrict__ W3,
    unsigned short* __restrict__ T0, unsigned short* __restrict__ T1,
    unsigned short* __restrict__ T2, unsigned short* __restrict__ T3)
{
    __shared__ float tl[32][33];
    const float* W = blockIdx.z==0?W0: blockIdx.z==1?W1: blockIdx.z==2?W2:W3;
    unsigned short* T = blockIdx.z==0?T0: blockIdx.z==1?T1: blockIdx.z==2?T2:T3;
    const int t = threadIdx.x;
    const int bk = blockIdx.x*32, bn = blockIdx.y*32;
    {
        int row = t>>3, c4 = (t&7)*4;
        float4 v = *(const float4*)&W[(size_t)(bk+row)*D_ + bn + c4];
        tl[row][c4+0]=v.x; tl[row][c4+1]=v.y; tl[row][c4+2]=v.z; tl[row][c4+3]=v.w;
    }
    __syncthreads();
    {
        int n = t>>3, k4 = (t&7)*4;
        unsigned a = cvtpk(tl[k4+0][n], tl[k4+1][n]);
        unsigned b = cvtpk(tl[k4+2][n], tl[k4+3][n]);
        u32x2 pk = {a, b};
        *(u32x2*)&T[(size_t)(bn+n)*D_ + bk + k4] = pk;
    }
}

// ---------------- bf16 MFMA GEMM: C = A[M,K] @ Bt[N,K]^T + bias ----------------
// MODE 0: f32 row-major out. MODE 1: bf16 head-major [B,H,S,DH] out, *scale.
// AF32 1: A is f32 (converted to bf16 during staging). AF32 0: A is bf16.
// Tile 128x128, BK=64, 4 waves (2x2), wave tile 64x64 (4x4 16x16 frags).
template<int MODE, int AF32>
__global__ __launch_bounds__(256) void gemm_mfma(
    const void* __restrict__ Av, const unsigned short* __restrict__ Btw,
    const float* __restrict__ bias, void* __restrict__ Cv, float scale)
{
    const int N_ = D_, K_ = D_;
    __shared__ __align__(16) char lds[32768];
    char* AsB = lds;            // As[128][64] bf16 swizzled
    char* BsB = lds + 16384;    // Bs[128][64] bf16 swizzled
    const int t = threadIdx.x;
    const int l = t & 63, wv = t>>6, g = l>>4, x = l&15;
    const int wr = wv>>1, wc = wv&1;
    const int br = blockIdx.y*128, bc = blockIdx.x*128;
    const float* Af = (const float*)Av;
    const unsigned short* Ab = (const unsigned short*)Av;

    int rw[4], bl[4];
    #pragma unroll
    for (int p=0;p<4;++p){ int u = t + 256*p; rw[p] = u>>3; bl[p] = u&7; }

    f4v acc[4][4];
    #pragma unroll
    for (int i=0;i<4;++i)
        #pragma unroll
        for (int j=0;j<4;++j) acc[i][j] = (f4v){0.f,0.f,0.f,0.f};

    float4 alo[4], ahi[4]; s8v arg[4]; s8v brg[4];
    // prologue: stage-load k-tile 0 into registers
    #pragma unroll
    for (int p=0;p<4;++p){
        if (AF32){
            const float* ap = Af + (size_t)(br+rw[p])*K_ + bl[p]*8;
            alo[p] = *(const float4*)ap; ahi[p] = *(const float4*)(ap+4);
        } else {
            arg[p] = *(const s8v*)(Ab + (size_t)(br+rw[p])*K_ + bl[p]*8);
        }
        brg[p] = *(const s8v*)(Btw + (size_t)(bc+rw[p])*K_ + bl[p]*8);
    }

    for (int kt=0; kt<K_; kt+=64){
        __syncthreads();
        #pragma unroll
        for (int p=0;p<4;++p){
            if (AF32){
                uint4 pk;
                pk.x = cvtpk(alo[p].x, alo[p].y); pk.y = cvtpk(alo[p].z, alo[p].w);
                pk.z = cvtpk(ahi[p].x, ahi[p].y); pk.w = cvtpk(ahi[p].z, ahi[p].w);
                *(uint4*)(AsB + swz(rw[p], bl[p])) = pk;
            } else {
                *(s8v*)(AsB + swz(rw[p], bl[p])) = arg[p];
            }
            *(s8v*)(BsB + swz(rw[p], bl[p])) = brg[p];
        }
        __syncthreads();
        if (kt + 64 < K_){   // T14: issue next tile's global loads; latency hides under MFMA
            #pragma unroll
            for (int p=0;p<4;++p){
                if (AF32){
                    const float* ap = Af + (size_t)(br+rw[p])*K_ + (kt+64) + bl[p]*8;
                    alo[p] = *(const float4*)ap; ahi[p] = *(const float4*)(ap+4);
                } else {
                    arg[p] = *(const s8v*)(Ab + (size_t)(br+rw[p])*K_ + (kt+64) + bl[p]*8);
                }
                brg[p] = *(const s8v*)(Btw + (size_t)(bc+rw[p])*K_ + (kt+64) + bl[p]*8);
            }
        }
        #pragma unroll
        for (int c=0;c<2;++c){
            s8v af[4], bf[4];
            #pragma unroll
            for (int fm=0; fm<4; ++fm)
                af[fm] = *(const s8v*)(AsB + swz(wr*64+fm*16+x, c*4+g));
            #pragma unroll
            for (int fn=0; fn<4; ++fn)
                bf[fn] = *(const s8v*)(BsB + swz(wc*64+fn*16+x, c*4+g));
            #pragma unroll
            for (int fm=0; fm<4; ++fm)
                #pragma unroll
                for (int fn=0; fn<4; ++fn)
                    acc[fm][fn] = __builtin_amdgcn_mfma_f32_16x16x32_bf16(
                        af[fm], bf[fn], acc[fm][fn], 0,0,0);
        }
    }

    #pragma unroll
    for (int fn=0; fn<4; ++fn){
        int col = bc + wc*64 + fn*16 + x;
        float bv = bias[col];
        #pragma unroll
        for (int fm=0; fm<4; ++fm){
            #pragma unroll
            for (int r=0;r<4;++r){
                int row = br + wr*64 + fm*16 + g*4 + r;
                float v = acc[fm][fn][r] + bv;
                if (MODE == 0){
                    ((float*)Cv)[(size_t)row*N_ + col] = v;
                } else {
                    int bI = row>>11, sI = row & (S_-1);
                    int hI = col>>6,  dhI = col & (DH_-1);
                    ((unsigned short*)Cv)[(((size_t)(bI*H_+hI))*S_+sI)*DH_+dhI]
                        = f2bf1(v*scale);
                }
            }
        }
    }
}

// ---------------- pair mean-pool along S (bf16, layout [B*H][S][DH]) ----------------
__global__ __launch_bounds__(256) void pool2_bf16(
    const unsigned short* __restrict__ in, unsigned short* __restrict__ out,
    int nOut4, int Sin)
{
    int idx = blockIdx.x * 256 + threadIdx.x;
    if (idx >= nOut4) return;
    int d0   = (idx & 15) * 4;
    int rest = idx >> 4;
    int Sout = Sin >> 1;
    int so = rest % Sout;
    int bh = rest / Sout;
    size_t base = ((size_t)bh * Sin + 2*so) * DH_ + d0;
    ushort4 a = *(const ushort4*)&in[base];
    ushort4 c = *(const ushort4*)&in[base + DH_];
    ushort4 o;
    o.x = f2bf1(0.5f*(bf2f(a.x)+bf2f(c.x)));
    o.y = f2bf1(0.5f*(bf2f(a.y)+bf2f(c.y)));
    o.z = f2bf1(0.5f*(bf2f(a.z)+bf2f(c.z)));
    o.w = f2bf1(0.5f*(bf2f(a.w)+bf2f(c.w)));
    *(ushort4*)&out[(size_t)idx*4] = o;
}

// ---------------- MFMA flash attention v2 ----------------
// 4 waves/block; wave w owns q-rows qt*64+w*16..+16. Swapped QK^T:
// s = mfma(K, Q) -> lane (g,x) holds S[q=x][key=f*16+g*4+r]: softmax is
// lane-local (15 ops) + 2 shfl_xor. P packed via cvt_pk, stored as 4x b64.
__global__ __launch_bounds__(256) void attn_mfma2(
    const unsigned short* __restrict__ qh,
    const unsigned short* __restrict__ kh0, const unsigned short* __restrict__ kh1,
    const unsigned short* __restrict__ kh2,
    const unsigned short* __restrict__ vh0, const unsigned short* __restrict__ vh1,
    const unsigned short* __restrict__ vh2,
    const float* __restrict__ wlv, unsigned short* __restrict__ accOut)
{
    __shared__ __align__(16) char ksB[8192];   // K  [key][dh] swizzled
    __shared__ __align__(16) char vsB[8192];   // V^T [dh][key] swizzled
    __shared__ __align__(16) char psm[8192];   // P per wave [q][key] swizzled
    const int t = threadIdx.x, l = t&63, wv = t>>6, g = l>>4, x = l&15;
    const int bid = blockIdx.x;
    const int qt = bid & 31, h = (bid>>5) & (H_-1), b = bid >> 9;
    char* psB = psm + wv*2048;

    const float w0 = wlv[0], w1 = wlv[1], w2 = wlv[2];
    const float winv = 1.f/(w0+w1+w2);

    // Q fragments (B-operand: n=q=x, k=c*32+g*8+j)
    const unsigned short* qp =
        qh + (((size_t)(b*H_+h))*S_ + (size_t)qt*64 + wv*16 + x)*DH_ + g*8;
    s8v qf0 = *(const s8v*)qp;
    s8v qf1 = *(const s8v*)(qp + 32);

    f4v accO[4];
    #pragma unroll
    for (int f=0; f<4; ++f) accO[f] = (f4v){0.f,0.f,0.f,0.f};

    // staging assignment: 2 chunks/thread covering 64 keys x 8 blocks
    const int lin0 = t,        r0 = lin0>>3, b0 = lin0&7;
    const int lin1 = t + 256,  r1 = lin1>>3, b1 = lin1&7;

    #pragma unroll 1
    for (int lvl = 0; lvl < 3; ++lvl) {
        const unsigned short *kp, *vp; int nt; float wc;
        if (lvl == 0)      { kp = kh0; vp = vh0; nt = 32; wc = w0; }
        else if (lvl == 1) { kp = kh1; vp = vh1; nt = 16; wc = w1; }
        else               { kp = kh2; vp = vh2; nt = 8;  wc = w2; }
        size_t hb = (size_t)(b*H_+h) * (size_t)(nt*64) * DH_;
        kp += hb; vp += hb;

        float m_i = -1e30f, l_i = 0.f;
        f4v o[4];
        #pragma unroll
        for (int f=0; f<4; ++f) o[f] = (f4v){0.f,0.f,0.f,0.f};

        // prologue stage-load tile 0
        s8v krg0 = *(const s8v*)(kp + (size_t)r0*DH_ + b0*8);
        s8v krg1 = *(const s8v*)(kp + (size_t)r1*DH_ + b1*8);
        s8v vrg0 = *(const s8v*)(vp + (size_t)r0*DH_ + b0*8);
        s8v vrg1 = *(const s8v*)(vp + (size_t)r1*DH_ + b1*8);

        for (int kt = 0; kt < nt; ++kt) {
            __syncthreads();   // prev tile's LDS reads done
            *(s8v*)(ksB + swz(r0, b0)) = krg0;
            *(s8v*)(ksB + swz(r1, b1)) = krg1;
            {   // V transpose scatter: vsm[d][key]
                int d00 = b0*8, d01 = b1*8;
                #pragma unroll
                for (int i=0;i<8;++i)
                    *(unsigned short*)(vsB + swz(d00+i, r0>>3) + ((r0&7)<<1))
                        = (unsigned short)vrg0[i];
                #pragma unroll
                for (int i=0;i<8;++i)
                    *(unsigned short*)(vsB + swz(d01+i, r1>>3) + ((r1&7)<<1))
                        = (unsigned short)vrg1[i];
            }
            __syncthreads();
            if (kt + 1 < nt) {   // T14: next tile's loads hide under compute
                size_t nb = (size_t)(kt+1)*64;
                krg0 = *(const s8v*)(kp + (nb+r0)*DH_ + b0*8);
                krg1 = *(const s8v*)(kp + (nb+r1)*DH_ + b1*8);
                vrg0 = *(const s8v*)(vp + (nb+r0)*DH_ + b0*8);
                vrg1 = *(const s8v*)(vp + (nb+r1)*DH_ + b1*8);
            }

            // ---- S^T = K @ Q^T : lane (g,x): s[f][r] = S[q=x][key=f*16+g*4+r] ----
            f4v s[4];
            #pragma unroll
            for (int f=0; f<4; ++f) s[f] = (f4v){0.f,0.f,0.f,0.f};
            #pragma unroll
            for (int c=0; c<2; ++c){
                s8v qf = c ? qf1 : qf0;
                #pragma unroll
                for (int f=0; f<4; ++f){
                    s8v kf = *(const s8v*)(ksB + swz(f*16 + x, c*4 + g));
                    s[f] = __builtin_amdgcn_mfma_f32_16x16x32_bf16(kf, qf, s[f], 0,0,0);
                }
            }

            // ---- online softmax (lane-local over 16, + g-group reduce) ----
            float pm = s[0][0];
            #pragma unroll
            for (int f=0; f<4; ++f)
                #pragma unroll
                for (int r=0; r<4; ++r) pm = fmaxf(pm, s[f][r]);
            pm = fmaxf(pm, __shfl_xor(pm, 16, 64));
            pm = fmaxf(pm, __shfl_xor(pm, 32, 64));
            float mn = fmaxf(m_i, pm);
            float corr = __expf(m_i - mn);
            m_i = mn;
            float p[4][4]; float rs = 0.f;
            #pragma unroll
            for (int f=0; f<4; ++f)
                #pragma unroll
                for (int r=0; r<4; ++r){ p[f][r] = __expf(s[f][r] - mn); rs += p[f][r]; }
            rs += __shfl_xor(rs, 16, 64);
            rs += __shfl_xor(rs, 32, 64);
            l_i = l_i*corr + rs;

            // ---- P -> psm (row q=x, keys f*16+g*4+0..3), vectorized b64 ----
            #pragma unroll
            for (int f=0; f<4; ++f){
                u32x2 pk;
                pk.x = cvtpk(p[f][0], p[f][1]);
                pk.y = cvtpk(p[f][2], p[f][3]);
                *(u32x2*)(psB + swz(x, 2*f + (g>>1)) + ((g&1)<<3)) = pk;
            }
            // same-wave ds_write->ds_read; DS pipe in-order, psm wave-private

            // ---- rescale O by corr (broadcast per q-row) ----
            float cb[4];
            #pragma unroll
            for (int r=0; r<4; ++r) cb[r] = __shfl(corr, g*4 + r, 64);
            #pragma unroll
            for (int f=0; f<4; ++f)
                #pragma unroll
                for (int r=0; r<4; ++r) o[f][r] *= cb[r];

            // ---- O += P @ V ----
            #pragma unroll
            for (int c=0; c<2; ++c){
                s8v pa = *(const s8v*)(psB + swz(x, c*4 + g));
                #pragma unroll
                for (int fd=0; fd<4; ++fd){
                    s8v vf = *(const s8v*)(vsB + swz(fd*16 + x, c*4 + g));
                    o[fd] = __builtin_amdgcn_mfma_f32_16x16x32_bf16(pa, vf, o[fd], 0,0,0);
                }
            }
        }

        float lb[4];
        #pragma unroll
        for (int r=0; r<4; ++r) lb[r] = __shfl(l_i, g*4 + r, 64);
        float wl = wc * winv;
        #pragma unroll
        for (int fd=0; fd<4; ++fd)
            #pragma unroll
            for (int r=0; r<4; ++r) accO[fd][r] += o[fd][r] * (wl / lb[r]);
    }

    #pragma unroll
    for (int r=0; r<4; ++r){
        size_t row = (size_t)b*S_ + (size_t)qt*64 + wv*16 + g*4 + r;
        #pragma unroll
        for (int fd=0; fd<4; ++fd)
            accOut[row*D_ + h*DH_ + fd*16 + x] = f2bf1(accO[fd][r]);
    }
}

// ---------------- launch ----------------
extern "C" void kernel_launch(void* const* d_in, const int* in_sizes, int n_in,
                              void* d_out, int out_size, void* d_ws, size_t ws_size,
                              hipStream_t stream)
{
    const float* query = (const float*)d_in[0];
    const float* key   = (const float*)d_in[1];
    const float* value = (const float*)d_in[2];
    const float* Wq = (const float*)d_in[3];  const float* bq = (const float*)d_in[4];
    const float* Wk = (const float*)d_in[5];  const float* bk = (const float*)d_in[6];
    const float* Wv = (const float*)d_in[7];  const float* bv = (const float*)d_in[8];
    const float* Wo = (const float*)d_in[9];  const float* bo = (const float*)d_in[10];
    const float* wlv = (const float*)d_in[11];

    char* w = (char*)d_ws;
    unsigned short* qhb  = (unsigned short*)(w);             // 8 MB [B,H,S,DH]
    unsigned short* khb0 = (unsigned short*)(w + 8388608);   // 8 MB
    unsigned short* khb1 = (unsigned short*)(w + 16777216);  // 4 MB
    unsigned short* khb2 = (unsigned short*)(w + 20971520);  // 2 MB
    unsigned short* vhb0 = (unsigned short*)(w + 23068672);  // 8 MB
    unsigned short* vhb1 = (unsigned short*)(w + 31457280);  // 4 MB
    unsigned short* vhb2 = (unsigned short*)(w + 35651584);  // 2 MB
    unsigned short* accb = (unsigned short*)(w + 37748736);  // 8 MB [B,S,D]
    unsigned short* Wtq  = (unsigned short*)(w + 46137344);  // 2 MB each
    unsigned short* Wtk  = (unsigned short*)(w + 48234496);
    unsigned short* Wtv  = (unsigned short*)(w + 50331648);
    unsigned short* Wto  = (unsigned short*)(w + 52428800);  // end 54525952

    dim3 bb(256);
    wtrans<<<dim3(32,32,4), bb, 0, stream>>>(Wq, Wk, Wv, Wo, Wtq, Wtk, Wtv, Wto);

    dim3 gg(D_/128, (B_*S_)/128);
    gemm_mfma<1,1><<<gg, bb, 0, stream>>>(query, Wtq, bq, qhb,  0.125f);
    gemm_mfma<1,1><<<gg, bb, 0, stream>>>(key,   Wtk, bk, khb0, 1.0f);
    gemm_mfma<1,1><<<gg, bb, 0, stream>>>(value, Wtv, bv, vhb0, 1.0f);

    int n1 = B_ * H_ * (S_/2) * DH_ / 4;   // 524288
    int n2 = B_ * H_ * (S_/4) * DH_ / 4;   // 262144
    pool2_bf16<<<n1/256, bb, 0, stream>>>(khb0, khb1, n1, S_);
    pool2_bf16<<<n2/256, bb, 0, stream>>>(khb1, khb2, n2, S_/2);
    pool2_bf16<<<n1/256, bb, 0, stream>>>(vhb0, vhb1, n1, S_);
    pool2_bf16<<<n2/256, bb, 0, stream>>>(vhb1, vhb2, n2, S_/2);

    attn_mfma2<<<B_*H_*(S_/64), bb, 0, stream>>>(qhb, khb0, khb1, khb2,
                                                 vhb0, vhb1, vhb2, wlv, accb);

    gemm_mfma<0,0><<<gg, bb, 0, stream>>>(accb, Wto, bo, d_out, 1.0f);
}

// Round 5
// 248.672 us; speedup vs baseline: 5.8307x; 1.0436x over previous
//
#include <hip/hip_runtime.h>

// Hierarchical 3-level pooled MHA. Round 5: round-4 pipeline (exp2/defer-max
// softmax, dbuf 1-barrier, setprio) with the PROVEN round-3 V scatter-transpose
// (tr64 read reverted — suspected output-packing mismatch caused R4 failure).
// B=2, S=2048, D=1024, H=16, DH=64.

#define B_  2
#define S_  2048
#define D_  1024
#define H_  16
#define DH_ 64
#define THR2 10.0f   // defer-max threshold, base-2 domain

typedef short s8v __attribute__((ext_vector_type(8)));   // 8 bf16
typedef float f4v __attribute__((ext_vector_type(4)));   // MFMA accum
typedef unsigned int u32x2 __attribute__((ext_vector_type(2)));

__device__ __forceinline__ unsigned cvtpk(float lo, float hi){
    unsigned r;
    asm volatile("v_cvt_pk_bf16_f32 %0, %1, %2" : "=v"(r) : "v"(lo), "v"(hi));
    return r;
}
__device__ __forceinline__ unsigned short f2bf1(float v){
    unsigned r;
    asm volatile("v_cvt_pk_bf16_f32 %0, %1, %2" : "=v"(r) : "v"(v), "v"(v));
    return (unsigned short)r;
}
__device__ __forceinline__ float bf2f(unsigned short h){
    union { unsigned u; float f; } v; v.u = ((unsigned)h) << 16;
    return v.f;
}
__device__ __forceinline__ float exp2_(float x){
    float r; asm("v_exp_f32 %0, %1" : "=v"(r) : "v"(x)); return r;
}
// XOR-swizzled byte offset of 16B block kb in row `row` of a [rows][64bf16] tile.
__device__ __forceinline__ int swz(int row, int kb){
    return row*128 + (((kb) ^ (row & 7) ^ ((row >> 3) & 7)) << 4);
}

// ---------------- W transpose + bf16 convert: Wt[n][k] = bf16(W[k][n]) ----------------
__global__ __launch_bounds__(256) void wtrans(
    const float* __restrict__ W0, const float* __restrict__ W1,
    const float* __restrict__ W2, const float* __restrict__ W3,
    unsigned short* __restrict__ T0, unsigned short* __restrict__ T1,
    unsigned short* __restrict__ T2, unsigned short* __restrict__ T3)
{
    __shared__ float tl[32][33];
    const float* W = blockIdx.z==0?W0: blockIdx.z==1?W1: blockIdx.z==2?W2:W3;
    unsigned short* T = blockIdx.z==0?T0: blockIdx.z==1?T1: blockIdx.z==2?T2:T3;
    const int t = threadIdx.x;
    const int bk = blockIdx.x*32, bn = blockIdx.y*32;
    {
        int row = t>>3, c4 = (t&7)*4;
        float4 v = *(const float4*)&W[(size_t)(bk+row)*D_ + bn + c4];
        tl[row][c4+0]=v.x; tl[row][c4+1]=v.y; tl[row][c4+2]=v.z; tl[row][c4+3]=v.w;
    }
    __syncthreads();
    {
        int n = t>>3, k4 = (t&7)*4;
        unsigned a = cvtpk(tl[k4+0][n], tl[k4+1][n]);
        unsigned b = cvtpk(tl[k4+2][n], tl[k4+3][n]);
        u32x2 pk = {a, b};
        *(u32x2*)&T[(size_t)(bn+n)*D_ + bk + k4] = pk;
    }
}

// ---------------- bf16 MFMA GEMM: C = A[M,K] @ Bt[N,K]^T + bias ----------------
// dbuf LDS, one barrier per K-step. MODE 0: f32 row-major out. MODE 1: bf16
// head-major [B,H,S,DH] out, *scale. AF32: A is f32, converted during staging.
template<int MODE, int AF32>
__global__ __launch_bounds__(256) void gemm_mfma(
    const void* __restrict__ Av, const unsigned short* __restrict__ Btw,
    const float* __restrict__ bias, void* __restrict__ Cv, float scale)
{
    const int N_ = D_, K_ = D_;
    __shared__ __align__(16) char lds[65536];    // [cur][A 16K | B 16K]
    const int t = threadIdx.x;
    const int l = t & 63, wv = t>>6, g = l>>4, x = l&15;
    const int wr = wv>>1, wc = wv&1;
    const int br = blockIdx.y*128, bc = blockIdx.x*128;
    const float* Af = (const float*)Av;
    const unsigned short* Ab = (const unsigned short*)Av;

    int rw[4], bl[4];
    #pragma unroll
    for (int p=0;p<4;++p){ int u = t + 256*p; rw[p] = u>>3; bl[p] = u&7; }

    f4v acc[4][4];
    #pragma unroll
    for (int i=0;i<4;++i)
        #pragma unroll
        for (int j=0;j<4;++j) acc[i][j] = (f4v){0.f,0.f,0.f,0.f};

    float4 alo[4], ahi[4]; s8v arg[4]; s8v brg[4];
    #pragma unroll
    for (int p=0;p<4;++p){
        if (AF32){
            const float* ap = Af + (size_t)(br+rw[p])*K_ + bl[p]*8;
            alo[p] = *(const float4*)ap; ahi[p] = *(const float4*)(ap+4);
        } else {
            arg[p] = *(const s8v*)(Ab + (size_t)(br+rw[p])*K_ + bl[p]*8);
        }
        brg[p] = *(const s8v*)(Btw + (size_t)(bc+rw[p])*K_ + bl[p]*8);
    }

    int cur = 0;
    for (int kt=0; kt<K_; kt+=64){
        char* AsB = lds + cur*32768;
        char* BsB = AsB + 16384;
        #pragma unroll
        for (int p=0;p<4;++p){
            if (AF32){
                uint4 pk;
                pk.x = cvtpk(alo[p].x, alo[p].y); pk.y = cvtpk(alo[p].z, alo[p].w);
                pk.z = cvtpk(ahi[p].x, ahi[p].y); pk.w = cvtpk(ahi[p].z, ahi[p].w);
                *(uint4*)(AsB + swz(rw[p], bl[p])) = pk;
            } else {
                *(s8v*)(AsB + swz(rw[p], bl[p])) = arg[p];
            }
            *(s8v*)(BsB + swz(rw[p], bl[p])) = brg[p];
        }
        if (kt + 64 < K_){   // T14: next tile's loads hide under MFMA
            #pragma unroll
            for (int p=0;p<4;++p){
                if (AF32){
                    const float* ap = Af + (size_t)(br+rw[p])*K_ + (kt+64) + bl[p]*8;
                    alo[p] = *(const float4*)ap; ahi[p] = *(const float4*)(ap+4);
                } else {
                    arg[p] = *(const s8v*)(Ab + (size_t)(br+rw[p])*K_ + (kt+64) + bl[p]*8);
                }
                brg[p] = *(const s8v*)(Btw + (size_t)(bc+rw[p])*K_ + (kt+64) + bl[p]*8);
            }
        }
        __syncthreads();
        #pragma unroll
        for (int c=0;c<2;++c){
            s8v af[4], bf[4];
            #pragma unroll
            for (int fm=0; fm<4; ++fm)
                af[fm] = *(const s8v*)(AsB + swz(wr*64+fm*16+x, c*4+g));
            #pragma unroll
            for (int fn=0; fn<4; ++fn)
                bf[fn] = *(const s8v*)(BsB + swz(wc*64+fn*16+x, c*4+g));
            __builtin_amdgcn_s_setprio(1);
            #pragma unroll
            for (int fm=0; fm<4; ++fm)
                #pragma unroll
                for (int fn=0; fn<4; ++fn)
                    acc[fm][fn] = __builtin_amdgcn_mfma_f32_16x16x32_bf16(
                        af[fm], bf[fn], acc[fm][fn], 0,0,0);
            __builtin_amdgcn_s_setprio(0);
        }
        cur ^= 1;
    }

    #pragma unroll
    for (int fn=0; fn<4; ++fn){
        int col = bc + wc*64 + fn*16 + x;
        float bv = bias[col];
        #pragma unroll
        for (int fm=0; fm<4; ++fm){
            #pragma unroll
            for (int r=0;r<4;++r){
                int row = br + wr*64 + fm*16 + g*4 + r;
                float v = acc[fm][fn][r] + bv;
                if (MODE == 0){
                    ((float*)Cv)[(size_t)row*N_ + col] = v;
                } else {
                    int bI = row>>11, sI = row & (S_-1);
                    int hI = col>>6,  dhI = col & (DH_-1);
                    ((unsigned short*)Cv)[(((size_t)(bI*H_+hI))*S_+sI)*DH_+dhI]
                        = f2bf1(v*scale);
                }
            }
        }
    }
}

// ---------------- pair mean-pool along S (bf16, layout [B*H][S][DH]) ----------------
__global__ __launch_bounds__(256) void pool2_bf16(
    const unsigned short* __restrict__ in, unsigned short* __restrict__ out,
    int nOut4, int Sin)
{
    int idx = blockIdx.x * 256 + threadIdx.x;
    if (idx >= nOut4) return;
    int d0   = (idx & 15) * 4;
    int rest = idx >> 4;
    int Sout = Sin >> 1;
    int so = rest % Sout;
    int bh = rest / Sout;
    size_t base = ((size_t)bh * Sin + 2*so) * DH_ + d0;
    ushort4 a = *(const ushort4*)&in[base];
    ushort4 c = *(const ushort4*)&in[base + DH_];
    ushort4 o;
    o.x = f2bf1(0.5f*(bf2f(a.x)+bf2f(c.x)));
    o.y = f2bf1(0.5f*(bf2f(a.y)+bf2f(c.y)));
    o.z = f2bf1(0.5f*(bf2f(a.z)+bf2f(c.z)));
    o.w = f2bf1(0.5f*(bf2f(a.w)+bf2f(c.w)));
    *(ushort4*)&out[(size_t)idx*4] = o;
}

// ---------------- MFMA flash attention v4 ----------------
// dbuf K/V (1 barrier/tile), V scatter-transposed to swz [d][key] (proven R3
// path), exp2-domain softmax + defer-max. Q pre-scaled by 0.125*log2(e).
__global__ __launch_bounds__(256, 4) void attn_mfma4(
    const unsigned short* __restrict__ qh,
    const unsigned short* __restrict__ kh0, const unsigned short* __restrict__ kh1,
    const unsigned short* __restrict__ kh2,
    const unsigned short* __restrict__ vh0, const unsigned short* __restrict__ vh1,
    const unsigned short* __restrict__ vh2,
    const float* __restrict__ wlv, unsigned short* __restrict__ accOut)
{
    __shared__ __align__(16) char ksm[2][8192];   // K [key][dh] swizzled
    __shared__ __align__(16) char vsm[2][8192];   // V^T [dh][key] swizzled
    __shared__ __align__(16) char psm[8192];      // P per wave [q][key] swizzled
    const int t = threadIdx.x, l = t&63, wv = t>>6, g = l>>4, x = l&15;
    const int bid = blockIdx.x;
    const int qt = bid & 31, h = (bid>>5) & (H_-1), b = bid >> 9;
    char* psB = psm + wv*2048;

    const float w0 = wlv[0], w1 = wlv[1], w2 = wlv[2];
    const float winv = 1.f/(w0+w1+w2);

    const unsigned short* qp =
        qh + (((size_t)(b*H_+h))*S_ + (size_t)qt*64 + wv*16 + x)*DH_ + g*8;
    s8v qf0 = *(const s8v*)qp;
    s8v qf1 = *(const s8v*)(qp + 32);

    // staging: chunk0 = (key r0, dblock b0); chunk1 = (key r0+32, dblock b0)
    const int r0 = t>>3, b0 = t&7;
    const int kOff0 = swz(r0, b0), kOff1 = swz(r0+32, b0);
    const int d00 = b0*8;

    f4v accO[4];
    #pragma unroll
    for (int f=0; f<4; ++f) accO[f] = (f4v){0.f,0.f,0.f,0.f};

    int cur = 0;
    #pragma unroll 1
    for (int lvl = 0; lvl < 3; ++lvl) {
        const unsigned short *kp, *vp; int nt; float wc;
        if (lvl == 0)      { kp = kh0; vp = vh0; nt = 32; wc = w0; }
        else if (lvl == 1) { kp = kh1; vp = vh1; nt = 16; wc = w1; }
        else               { kp = kh2; vp = vh2; nt = 8;  wc = w2; }
        size_t hb = (size_t)(b*H_+h) * (size_t)(nt*64) * DH_;
        kp += hb; vp += hb;

        float m_i = -1e30f, l_i = 0.f;
        f4v o[4];
        #pragma unroll
        for (int f=0; f<4; ++f) o[f] = (f4v){0.f,0.f,0.f,0.f};

        // prologue: tile 0 into regs
        s8v krg0 = *(const s8v*)(kp + (size_t)r0*DH_ + b0*8);
        s8v krg1 = *(const s8v*)(kp + (size_t)(r0+32)*DH_ + b0*8);
        s8v vrg0 = *(const s8v*)(vp + (size_t)r0*DH_ + b0*8);
        s8v vrg1 = *(const s8v*)(vp + (size_t)(r0+32)*DH_ + b0*8);

        for (int kt = 0; kt < nt; ++kt) {
            char* kb_ = ksm[cur];
            char* vb_ = vsm[cur];
            *(s8v*)(kb_ + kOff0) = krg0;
            *(s8v*)(kb_ + kOff1) = krg1;
            #pragma unroll
            for (int i=0;i<8;++i)   // V transpose scatter: vsm[d][key]
                *(unsigned short*)(vb_ + swz(d00+i, r0>>3) + ((r0&7)<<1))
                    = (unsigned short)vrg0[i];
            #pragma unroll
            for (int i=0;i<8;++i)
                *(unsigned short*)(vb_ + swz(d00+i, (r0>>3)+4) + ((r0&7)<<1))
                    = (unsigned short)vrg1[i];
            if (kt + 1 < nt) {   // T14: next tile's loads hide under compute
                size_t nb = (size_t)(kt+1)*64;
                krg0 = *(const s8v*)(kp + (nb+r0)*DH_ + b0*8);
                krg1 = *(const s8v*)(kp + (nb+r0+32)*DH_ + b0*8);
                vrg0 = *(const s8v*)(vp + (nb+r0)*DH_ + b0*8);
                vrg1 = *(const s8v*)(vp + (nb+r0+32)*DH_ + b0*8);
            }
            __syncthreads();

            // ---- S^T = K @ Q^T (base-2 scaled) ----
            f4v s[4];
            #pragma unroll
            for (int f=0; f<4; ++f) s[f] = (f4v){0.f,0.f,0.f,0.f};
            #pragma unroll
            for (int c=0; c<2; ++c){
                s8v qf = c ? qf1 : qf0;
                s8v kf[4];
                #pragma unroll
                for (int f=0; f<4; ++f)
                    kf[f] = *(const s8v*)(kb_ + swz(f*16 + x, c*4 + g));
                __builtin_amdgcn_s_setprio(1);
                #pragma unroll
                for (int f=0; f<4; ++f)
                    s[f] = __builtin_amdgcn_mfma_f32_16x16x32_bf16(kf[f], qf, s[f], 0,0,0);
                __builtin_amdgcn_s_setprio(0);
            }

            // ---- online softmax, exp2 domain, defer-max ----
            float pm;
            {
                float a0 = fmaxf(fmaxf(s[0][0],s[0][1]), fmaxf(s[0][2],s[0][3]));
                float a1 = fmaxf(fmaxf(s[1][0],s[1][1]), fmaxf(s[1][2],s[1][3]));
                float a2 = fmaxf(fmaxf(s[2][0],s[2][1]), fmaxf(s[2][2],s[2][3]));
                float a3 = fmaxf(fmaxf(s[3][0],s[3][1]), fmaxf(s[3][2],s[3][3]));
                pm = fmaxf(fmaxf(a0,a1), fmaxf(a2,a3));
            }
            pm = fmaxf(pm, __shfl_xor(pm, 16, 64));
            pm = fmaxf(pm, __shfl_xor(pm, 32, 64));
            if (__any(pm > m_i + THR2)) {
                float mn = fmaxf(m_i, pm);
                float corr = exp2_(m_i - mn);
                m_i = mn;
                l_i *= corr;
                float cb[4];
                #pragma unroll
                for (int r=0; r<4; ++r) cb[r] = __shfl(corr, g*4 + r, 64);
                #pragma unroll
                for (int f=0; f<4; ++f)
                    #pragma unroll
                    for (int r=0; r<4; ++r) o[f][r] *= cb[r];
            }
            float p[4][4]; float rs = 0.f;
            #pragma unroll
            for (int f=0; f<4; ++f)
                #pragma unroll
                for (int r=0; r<4; ++r){ p[f][r] = exp2_(s[f][r] - m_i); rs += p[f][r]; }
            rs += __shfl_xor(rs, 16, 64);
            rs += __shfl_xor(rs, 32, 64);
            l_i += rs;

            // ---- P -> psm (row q=x, keys f*16+g*4+0..3) ----
            #pragma unroll
            for (int f=0; f<4; ++f){
                u32x2 pk;
                pk.x = cvtpk(p[f][0], p[f][1]);
                pk.y = cvtpk(p[f][2], p[f][3]);
                *(u32x2*)(psB + swz(x, 2*f + (g>>1)) + ((g&1)<<3)) = pk;
            }
            // same-wave ds_write->ds_read; DS pipe in-order, psm wave-private

            // ---- O += P @ V ----
            #pragma unroll
            for (int c=0; c<2; ++c){
                s8v pa = *(const s8v*)(psB + swz(x, c*4 + g));
                s8v vf[4];
                #pragma unroll
                for (int fd=0; fd<4; ++fd)
                    vf[fd] = *(const s8v*)(vb_ + swz(fd*16 + x, c*4 + g));
                __builtin_amdgcn_s_setprio(1);
                #pragma unroll
                for (int fd=0; fd<4; ++fd)
                    o[fd] = __builtin_amdgcn_mfma_f32_16x16x32_bf16(pa, vf[fd], o[fd], 0,0,0);
                __builtin_amdgcn_s_setprio(0);
            }
            cur ^= 1;
        }

        float lb[4];
        #pragma unroll
        for (int r=0; r<4; ++r) lb[r] = __shfl(l_i, g*4 + r, 64);
        float wl = wc * winv;
        #pragma unroll
        for (int fd=0; fd<4; ++fd)
            #pragma unroll
            for (int r=0; r<4; ++r) accO[fd][r] += o[fd][r] * (wl / lb[r]);
    }

    #pragma unroll
    for (int r=0; r<4; ++r){
        size_t row = (size_t)b*S_ + (size_t)qt*64 + wv*16 + g*4 + r;
        #pragma unroll
        for (int fd=0; fd<4; ++fd)
            accOut[row*D_ + h*DH_ + fd*16 + x] = f2bf1(accO[fd][r]);
    }
}

// ---------------- launch ----------------
extern "C" void kernel_launch(void* const* d_in, const int* in_sizes, int n_in,
                              void* d_out, int out_size, void* d_ws, size_t ws_size,
                              hipStream_t stream)
{
    const float* query = (const float*)d_in[0];
    const float* key   = (const float*)d_in[1];
    const float* value = (const float*)d_in[2];
    const float* Wq = (const float*)d_in[3];  const float* bq = (const float*)d_in[4];
    const float* Wk = (const float*)d_in[5];  const float* bk = (const float*)d_in[6];
    const float* Wv = (const float*)d_in[7];  const float* bv = (const float*)d_in[8];
    const float* Wo = (const float*)d_in[9];  const float* bo = (const float*)d_in[10];
    const float* wlv = (const float*)d_in[11];

    char* w = (char*)d_ws;
    unsigned short* qhb  = (unsigned short*)(w);             // 8 MB [B,H,S,DH]
    unsigned short* khb0 = (unsigned short*)(w + 8388608);   // 8 MB
    unsigned short* khb1 = (unsigned short*)(w + 16777216);  // 4 MB
    unsigned short* khb2 = (unsigned short*)(w + 20971520);  // 2 MB
    unsigned short* vhb0 = (unsigned short*)(w + 23068672);  // 8 MB
    unsigned short* vhb1 = (unsigned short*)(w + 31457280);  // 4 MB
    unsigned short* vhb2 = (unsigned short*)(w + 35651584);  // 2 MB
    unsigned short* accb = (unsigned short*)(w + 37748736);  // 8 MB [B,S,D]
    unsigned short* Wtq  = (unsigned short*)(w + 46137344);  // 2 MB each
    unsigned short* Wtk  = (unsigned short*)(w + 48234496);
    unsigned short* Wtv  = (unsigned short*)(w + 50331648);
    unsigned short* Wto  = (unsigned short*)(w + 52428800);  // end 54525952

    dim3 bb(256);
    wtrans<<<dim3(32,32,4), bb, 0, stream>>>(Wq, Wk, Wv, Wo, Wtq, Wtk, Wtv, Wto);

    const float scale_q = 0.125f * 1.44269504088896f;   // 1/sqrt(DH) * log2(e)
    dim3 gg(D_/128, (B_*S_)/128);
    gemm_mfma<1,1><<<gg, bb, 0, stream>>>(query, Wtq, bq, qhb,  scale_q);
    gemm_mfma<1,1><<<gg, bb, 0, stream>>>(key,   Wtk, bk, khb0, 1.0f);
    gemm_mfma<1,1><<<gg, bb, 0, stream>>>(value, Wtv, bv, vhb0, 1.0f);

    int n1 = B_ * H_ * (S_/2) * DH_ / 4;   // 524288
    int n2 = B_ * H_ * (S_/4) * DH_ / 4;   // 262144
    pool2_bf16<<<n1/256, bb, 0, stream>>>(khb0, khb1, n1, S_);
    pool2_bf16<<<n2/256, bb, 0, stream>>>(khb1, khb2, n2, S_/2);
    pool2_bf16<<<n1/256, bb, 0, stream>>>(vhb0, vhb1, n1, S_);
    pool2_bf16<<<n2/256, bb, 0, stream>>>(vhb1, vhb2, n2, S_/2);

    attn_mfma4<<<B_*H_*(S_/64), bb, 0, stream>>>(qhb, khb0, khb1, khb2,
                                                 vhb0, vhb1, vhb2, wlv, accb);

    gemm_mfma<0,0><<<gg, bb, 0, stream>>>(accb, Wto, bo, d_out, 1.0f);
}

// Round 7
// 189.526 us; speedup vs baseline: 7.6503x; 1.3121x over previous
//
#include <hip/hip_runtime.h>

// Hierarchical 3-level pooled MHA. Round 7: R6 structure with pswap operand
// order FIXED (v_permlane32_swap_b32 swaps dst[32:63] <-> src[0:31]).
// B=2, S=2048, D=1024, H=16, DH=64.

#define B_  2
#define S_  2048
#define D_  1024
#define H_  16
#define DH_ 64
#define THR2 10.0f   // defer-max threshold, base-2 domain

typedef short s8v __attribute__((ext_vector_type(8)));    // 8 bf16
typedef float f4v __attribute__((ext_vector_type(4)));
typedef float f16v __attribute__((ext_vector_type(16)));  // 32x32 accum
typedef unsigned int u32x2 __attribute__((ext_vector_type(2)));
typedef unsigned int u32x4 __attribute__((ext_vector_type(4)));

__device__ __forceinline__ unsigned cvtpk(float lo, float hi){
    unsigned r;
    asm volatile("v_cvt_pk_bf16_f32 %0, %1, %2" : "=v"(r) : "v"(lo), "v"(hi));
    return r;
}
__device__ __forceinline__ unsigned short f2bf1(float v){
    unsigned r;
    asm volatile("v_cvt_pk_bf16_f32 %0, %1, %2" : "=v"(r) : "v"(v), "v"(v));
    return (unsigned short)r;
}
__device__ __forceinline__ float bf2f(unsigned short h){
    union { unsigned u; float f; } v; v.u = ((unsigned)h) << 16;
    return v.f;
}
__device__ __forceinline__ float exp2_(float x){
    float r; asm("v_exp_f32 %0, %1" : "=v"(r) : "v"(x)); return r;
}
// v_permlane32_swap_b32 vdst, vsrc: vdst[32:63] <-> vsrc[0:31] (both updated).
__device__ __forceinline__ void pswap(unsigned &dst, unsigned &src){
    asm volatile("v_permlane32_swap_b32 %0, %1" : "+v"(dst), "+v"(src));
}
// XOR-swizzled byte offset of 16B block kb in row `row` of a [rows][64bf16] tile.
__device__ __forceinline__ int swz(int row, int kb){
    return row*128 + (((kb) ^ (row & 7) ^ ((row >> 3) & 7)) << 4);
}

// ---------------- W transpose + bf16 convert: Wt[n][k] = bf16(W[k][n]) ----------------
__global__ __launch_bounds__(256) void wtrans(
    const float* __restrict__ W0, const float* __restrict__ W1,
    const float* __restrict__ W2, const float* __restrict__ W3,
    unsigned short* __restrict__ T0, unsigned short* __restrict__ T1,
    unsigned short* __restrict__ T2, unsigned short* __restrict__ T3)
{
    __shared__ float tl[32][33];
    const float* W = blockIdx.z==0?W0: blockIdx.z==1?W1: blockIdx.z==2?W2:W3;
    unsigned short* T = blockIdx.z==0?T0: blockIdx.z==1?T1: blockIdx.z==2?T2:T3;
    const int t = threadIdx.x;
    const int bk = blockIdx.x*32, bn = blockIdx.y*32;
    {
        int row = t>>3, c4 = (t&7)*4;
        float4 v = *(const float4*)&W[(size_t)(bk+row)*D_ + bn + c4];
        tl[row][c4+0]=v.x; tl[row][c4+1]=v.y; tl[row][c4+2]=v.z; tl[row][c4+3]=v.w;
    }
    __syncthreads();
    {
        int n = t>>3, k4 = (t&7)*4;
        unsigned a = cvtpk(tl[k4+0][n], tl[k4+1][n]);
        unsigned b = cvtpk(tl[k4+2][n], tl[k4+3][n]);
        u32x2 pk = {a, b};
        *(u32x2*)&T[(size_t)(bn+n)*D_ + bk + k4] = pk;
    }
}

// ---------------- bf16 MFMA GEMM: C = A[M,K] @ Bt[N,K]^T + bias ----------------
// MODE 0: f32 row-major. MODE 1: bf16 head-major [B,H,S,DH], *scale.
// MODE 2: bf16 TRANSPOSED head-major [B,H,DH,S], *scale (packed 8B stores).
// AF32: A is f32, converted to bf16 during staging.
template<int MODE, int AF32>
__global__ __launch_bounds__(256) void gemm_mfma(
    const void* __restrict__ Av, const unsigned short* __restrict__ Btw,
    const float* __restrict__ bias, void* __restrict__ Cv, float scale)
{
    const int N_ = D_, K_ = D_;
    __shared__ __align__(16) char lds[65536];    // dbuf: [cur][A 16K | B 16K]
    const int t = threadIdx.x;
    const int l = t & 63, wv = t>>6, g = l>>4, x = l&15;
    const int wr = wv>>1, wc = wv&1;
    const int br = blockIdx.y*128, bc = blockIdx.x*128;
    const float* Af = (const float*)Av;
    const unsigned short* Ab = (const unsigned short*)Av;

    int rw[4], bl[4];
    #pragma unroll
    for (int p=0;p<4;++p){ int u = t + 256*p; rw[p] = u>>3; bl[p] = u&7; }

    f4v acc[4][4];
    #pragma unroll
    for (int i=0;i<4;++i)
        #pragma unroll
        for (int j=0;j<4;++j) acc[i][j] = (f4v){0.f,0.f,0.f,0.f};

    float4 alo[4], ahi[4]; s8v arg[4]; s8v brg[4];
    #pragma unroll
    for (int p=0;p<4;++p){
        if (AF32){
            const float* ap = Af + (size_t)(br+rw[p])*K_ + bl[p]*8;
            alo[p] = *(const float4*)ap; ahi[p] = *(const float4*)(ap+4);
        } else {
            arg[p] = *(const s8v*)(Ab + (size_t)(br+rw[p])*K_ + bl[p]*8);
        }
        brg[p] = *(const s8v*)(Btw + (size_t)(bc+rw[p])*K_ + bl[p]*8);
    }

    int cur = 0;
    for (int kt=0; kt<K_; kt+=64){
        char* AsB = lds + cur*32768;
        char* BsB = AsB + 16384;
        #pragma unroll
        for (int p=0;p<4;++p){
            if (AF32){
                uint4 pk;
                pk.x = cvtpk(alo[p].x, alo[p].y); pk.y = cvtpk(alo[p].z, alo[p].w);
                pk.z = cvtpk(ahi[p].x, ahi[p].y); pk.w = cvtpk(ahi[p].z, ahi[p].w);
                *(uint4*)(AsB + swz(rw[p], bl[p])) = pk;
            } else {
                *(s8v*)(AsB + swz(rw[p], bl[p])) = arg[p];
            }
            *(s8v*)(BsB + swz(rw[p], bl[p])) = brg[p];
        }
        if (kt + 64 < K_){
            #pragma unroll
            for (int p=0;p<4;++p){
                if (AF32){
                    const float* ap = Af + (size_t)(br+rw[p])*K_ + (kt+64) + bl[p]*8;
                    alo[p] = *(const float4*)ap; ahi[p] = *(const float4*)(ap+4);
                } else {
                    arg[p] = *(const s8v*)(Ab + (size_t)(br+rw[p])*K_ + (kt+64) + bl[p]*8);
                }
                brg[p] = *(const s8v*)(Btw + (size_t)(bc+rw[p])*K_ + (kt+64) + bl[p]*8);
            }
        }
        __syncthreads();
        #pragma unroll
        for (int c=0;c<2;++c){
            s8v af[4], bf[4];
            #pragma unroll
            for (int fm=0; fm<4; ++fm)
                af[fm] = *(const s8v*)(AsB + swz(wr*64+fm*16+x, c*4+g));
            #pragma unroll
            for (int fn=0; fn<4; ++fn)
                bf[fn] = *(const s8v*)(BsB + swz(wc*64+fn*16+x, c*4+g));
            __builtin_amdgcn_s_setprio(1);
            #pragma unroll
            for (int fm=0; fm<4; ++fm)
                #pragma unroll
                for (int fn=0; fn<4; ++fn)
                    acc[fm][fn] = __builtin_amdgcn_mfma_f32_16x16x32_bf16(
                        af[fm], bf[fn], acc[fm][fn], 0,0,0);
            __builtin_amdgcn_s_setprio(0);
        }
        cur ^= 1;
    }

    #pragma unroll
    for (int fn=0; fn<4; ++fn){
        int col = bc + wc*64 + fn*16 + x;
        float bv = bias[col];
        #pragma unroll
        for (int fm=0; fm<4; ++fm){
            int row0 = br + wr*64 + fm*16 + g*4;
            float v0 = (acc[fm][fn][0] + bv);
            float v1 = (acc[fm][fn][1] + bv);
            float v2 = (acc[fm][fn][2] + bv);
            float v3 = (acc[fm][fn][3] + bv);
            if (MODE == 0){
                float* C = (float*)Cv;
                C[(size_t)(row0+0)*N_ + col] = v0;
                C[(size_t)(row0+1)*N_ + col] = v1;
                C[(size_t)(row0+2)*N_ + col] = v2;
                C[(size_t)(row0+3)*N_ + col] = v3;
            } else if (MODE == 1){
                unsigned short* C = (unsigned short*)Cv;
                int hI = col>>6, dhI = col & (DH_-1);
                #pragma unroll
                for (int r=0;r<4;++r){
                    int row = row0 + r;
                    int bI = row>>11, sI = row & (S_-1);
                    float vv = (r==0?v0: r==1?v1: r==2?v2: v3) * scale;
                    C[(((size_t)(bI*H_+hI))*S_+sI)*DH_+dhI] = f2bf1(vv);
                }
            } else {  // MODE 2: [B,H,DH,S], 4 consecutive tokens -> 8B store
                unsigned short* C = (unsigned short*)Cv;
                int bI = row0>>11, sI = row0 & (S_-1);
                int hI = col>>6, dhI = col & (DH_-1);
                u32x2 pk;
                pk.x = cvtpk(v0*scale, v1*scale);
                pk.y = cvtpk(v2*scale, v3*scale);
                *(u32x2*)&C[(((size_t)(bI*H_+hI))*DH_+dhI)*S_ + sI] = pk;
            }
        }
    }
}

// ---------------- K pools: pair mean along S, layout [B*H][S][DH] ----------------
__global__ __launch_bounds__(256) void pool2_bf16(
    const unsigned short* __restrict__ in, unsigned short* __restrict__ out,
    int nOut4, int Sin)
{
    int idx = blockIdx.x * 256 + threadIdx.x;
    if (idx >= nOut4) return;
    int d0   = (idx & 15) * 4;
    int rest = idx >> 4;
    int Sout = Sin >> 1;
    int so = rest % Sout;
    int bh = rest / Sout;
    size_t base = ((size_t)bh * Sin + 2*so) * DH_ + d0;
    ushort4 a = *(const ushort4*)&in[base];
    ushort4 c = *(const ushort4*)&in[base + DH_];
    ushort4 o;
    o.x = f2bf1(0.5f*(bf2f(a.x)+bf2f(c.x)));
    o.y = f2bf1(0.5f*(bf2f(a.y)+bf2f(c.y)));
    o.z = f2bf1(0.5f*(bf2f(a.z)+bf2f(c.z)));
    o.w = f2bf1(0.5f*(bf2f(a.w)+bf2f(c.w)));
    *(ushort4*)&out[(size_t)idx*4] = o;
}

// ---------------- V pools on transposed layout [B*H*DH][S]: adjacent pair mean ----------------
// shift = log2(Sout/4). Each thread: 8 bf16 in -> 4 bf16 out.
__global__ __launch_bounds__(256) void pool2T(
    const unsigned short* __restrict__ in, unsigned short* __restrict__ out,
    int nOut4, int Sin, int shift)
{
    int idx = blockIdx.x * 256 + threadIdx.x;
    if (idx >= nOut4) return;
    int row = idx >> shift;
    int so4 = (idx & ((1<<shift)-1)) << 2;
    union { u32x4 u; unsigned short h[8]; } a;
    a.u = *(const u32x4*)&in[(size_t)row*Sin + so4*2];
    float m0 = 0.5f*(bf2f(a.h[0])+bf2f(a.h[1]));
    float m1 = 0.5f*(bf2f(a.h[2])+bf2f(a.h[3]));
    float m2 = 0.5f*(bf2f(a.h[4])+bf2f(a.h[5]));
    float m3 = 0.5f*(bf2f(a.h[6])+bf2f(a.h[7]));
    u32x2 pk; pk.x = cvtpk(m0,m1); pk.y = cvtpk(m2,m3);
    *(u32x2*)&out[(size_t)row*(Sin>>1) + so4] = pk;
}

// ---------------- MFMA flash attention v5: 32x32, in-register P ----------------
// 4 waves x 32 q-rows = 128 q/block; KV tile 64, dbuf, 1 barrier/tile.
// lane: q = l&31, hi = l>>5. QK^T: s = mfma32(K,Q) -> s[r] = S[key=crow(r)+4hi+kg*32][q].
// P-frag via cvt_pk + permlane32_swap (no LDS). PV: o = mfma32(P, V^T-frag).
__global__ __launch_bounds__(256, 2) void attn_mfma5(
    const unsigned short* __restrict__ qh,
    const unsigned short* __restrict__ kh0, const unsigned short* __restrict__ kh1,
    const unsigned short* __restrict__ kh2,
    const unsigned short* __restrict__ vt0, const unsigned short* __restrict__ vt1,
    const unsigned short* __restrict__ vt2,
    const float* __restrict__ wlv, unsigned short* __restrict__ accOut)
{
    __shared__ __align__(16) char ksm[2][8192];   // K  [key][dh] swizzled
    __shared__ __align__(16) char vsm[2][8192];   // V^T [dh][key] swizzled
    const int t = threadIdx.x, l = t&63, wv = t>>6, q = l&31, hi = l>>5;
    const int bid = blockIdx.x;
    const int qt = bid & 15, h = (bid>>4) & (H_-1), b = bid >> 8;

    const float w0 = wlv[0], w1 = wlv[1], w2 = wlv[2];
    const float winv = 1.f/(w0+w1+w2);

    // Q fragments (B-operand): qf[dc][j] = Q[q][dc*16 + hi*8 + j]
    const unsigned short* qp =
        qh + (((size_t)(b*H_+h))*S_ + (size_t)qt*128 + wv*32 + q)*DH_ + hi*8;
    s8v qf0 = *(const s8v*)(qp);
    s8v qf1 = *(const s8v*)(qp + 16);
    s8v qf2 = *(const s8v*)(qp + 32);
    s8v qf3 = *(const s8v*)(qp + 48);

    // staging: thread covers rows r0 and r0+32, 16B block kb (same offs for K and V^T)
    const int r0 = t>>3, kb = t&7;
    const int off0 = swz(r0, kb), off1 = swz(r0+32, kb);

    f16v aO0, aO1;
    #pragma unroll
    for (int r=0;r<16;++r){ aO0[r]=0.f; aO1[r]=0.f; }

    int cur = 0;
    #pragma unroll 1
    for (int lvl = 0; lvl < 3; ++lvl) {
        const unsigned short *kp, *vpt; int nt; float wc;
        if (lvl == 0)      { kp = kh0; vpt = vt0; nt = 32; wc = w0; }
        else if (lvl == 1) { kp = kh1; vpt = vt1; nt = 16; wc = w1; }
        else               { kp = kh2; vpt = vt2; nt = 8;  wc = w2; }
        const int Sl = nt*64;
        const unsigned short* kbase = kp + (size_t)(b*H_+h)*Sl*DH_;
        const unsigned short* v0r = vpt + ((size_t)(b*H_+h)*DH_ + r0)*Sl;
        const unsigned short* v1r = vpt + ((size_t)(b*H_+h)*DH_ + r0+32)*Sl;

        float m_i = -1e30f, l_i = 0.f;
        f16v o0, o1;
        #pragma unroll
        for (int r=0;r<16;++r){ o0[r]=0.f; o1[r]=0.f; }

        // prologue: tile 0 -> regs
        s8v krg0 = *(const s8v*)(kbase + (size_t)r0*DH_ + kb*8);
        s8v krg1 = *(const s8v*)(kbase + (size_t)(r0+32)*DH_ + kb*8);
        s8v vrg0 = *(const s8v*)(v0r + kb*8);
        s8v vrg1 = *(const s8v*)(v1r + kb*8);

        for (int kt = 0; kt < nt; ++kt) {
            char* kb_ = ksm[cur];
            char* vb_ = vsm[cur];
            *(s8v*)(kb_ + off0) = krg0;
            *(s8v*)(kb_ + off1) = krg1;
            *(s8v*)(vb_ + off0) = vrg0;
            *(s8v*)(vb_ + off1) = vrg1;
            if (kt + 1 < nt) {
                size_t nb = (size_t)(kt+1)*64;
                krg0 = *(const s8v*)(kbase + (nb+r0)*DH_ + kb*8);
                krg1 = *(const s8v*)(kbase + (nb+r0+32)*DH_ + kb*8);
                vrg0 = *(const s8v*)(v0r + nb + kb*8);
                vrg1 = *(const s8v*)(v1r + nb + kb*8);
            }
            __syncthreads();

            // ---- S^T = K @ Q^T (base-2 scaled), 2 key-groups x 4 dh-chunks ----
            f16v s0, s1;
            #pragma unroll
            for (int r=0;r<16;++r){ s0[r]=0.f; s1[r]=0.f; }
            {
                s8v k00 = *(const s8v*)(kb_ + swz(q,      0*2+hi));
                s8v k01 = *(const s8v*)(kb_ + swz(q,      1*2+hi));
                s8v k02 = *(const s8v*)(kb_ + swz(q,      2*2+hi));
                s8v k03 = *(const s8v*)(kb_ + swz(q,      3*2+hi));
                s8v k10 = *(const s8v*)(kb_ + swz(32+q,   0*2+hi));
                s8v k11 = *(const s8v*)(kb_ + swz(32+q,   1*2+hi));
                s8v k12 = *(const s8v*)(kb_ + swz(32+q,   2*2+hi));
                s8v k13 = *(const s8v*)(kb_ + swz(32+q,   3*2+hi));
                __builtin_amdgcn_s_setprio(1);
                s0 = __builtin_amdgcn_mfma_f32_32x32x16_bf16(k00, qf0, s0, 0,0,0);
                s1 = __builtin_amdgcn_mfma_f32_32x32x16_bf16(k10, qf0, s1, 0,0,0);
                s0 = __builtin_amdgcn_mfma_f32_32x32x16_bf16(k01, qf1, s0, 0,0,0);
                s1 = __builtin_amdgcn_mfma_f32_32x32x16_bf16(k11, qf1, s1, 0,0,0);
                s0 = __builtin_amdgcn_mfma_f32_32x32x16_bf16(k02, qf2, s0, 0,0,0);
                s1 = __builtin_amdgcn_mfma_f32_32x32x16_bf16(k12, qf2, s1, 0,0,0);
                s0 = __builtin_amdgcn_mfma_f32_32x32x16_bf16(k03, qf3, s0, 0,0,0);
                s1 = __builtin_amdgcn_mfma_f32_32x32x16_bf16(k13, qf3, s1, 0,0,0);
                __builtin_amdgcn_s_setprio(0);
            }

            // ---- online softmax (exp2 domain, defer-max); lane owns one q ----
            float pm = s0[0];
            #pragma unroll
            for (int r=1;r<16;++r) pm = fmaxf(pm, s0[r]);
            #pragma unroll
            for (int r=0;r<16;++r) pm = fmaxf(pm, s1[r]);
            pm = fmaxf(pm, __shfl_xor(pm, 32, 64));
            if (__any(pm > m_i + THR2)) {
                float mn = fmaxf(m_i, pm);
                float corr = exp2_(m_i - mn);
                m_i = mn;
                l_i *= corr;
                #pragma unroll
                for (int r=0;r<16;++r){
                    float cb = __shfl(corr, ((r&3)+8*(r>>2)) + 4*hi, 64);
                    o0[r] *= cb; o1[r] *= cb;
                }
            }
            float rs = 0.f;
            #pragma unroll
            for (int r=0;r<16;++r){ s0[r] = exp2_(s0[r]-m_i); rs += s0[r]; }
            #pragma unroll
            for (int r=0;r<16;++r){ s1[r] = exp2_(s1[r]-m_i); rs += s1[r]; }
            rs += __shfl_xor(rs, 32, 64);
            l_i += rs;

            // ---- P-frags in-register: cvt_pk pairs + permlane32_swap ----
            // pswap(X, Y): X[32:63] <-> Y[0:31]. After pswap(a0,b0):
            //   a0 = {lo: keys(4hi..)|hi=0, hi: keys(8+..)|hi=0} = A-word0
            //   b0 = {lo: keys(4..5)|hi=1 side, ...}            = A-word2
            unsigned a0 = cvtpk(s0[0], s0[1]),  a1 = cvtpk(s0[2], s0[3]);
            unsigned b0 = cvtpk(s0[4], s0[5]),  b1 = cvtpk(s0[6], s0[7]);
            pswap(a0, b0); pswap(a1, b1);
            unsigned c0 = cvtpk(s0[8], s0[9]),  c1 = cvtpk(s0[10], s0[11]);
            unsigned d0 = cvtpk(s0[12], s0[13]),d1 = cvtpk(s0[14], s0[15]);
            pswap(c0, d0); pswap(c1, d1);
            unsigned e0 = cvtpk(s1[0], s1[1]),  e1 = cvtpk(s1[2], s1[3]);
            unsigned f0 = cvtpk(s1[4], s1[5]),  f1 = cvtpk(s1[6], s1[7]);
            pswap(e0, f0); pswap(e1, f1);
            unsigned g0 = cvtpk(s1[8], s1[9]),  g1 = cvtpk(s1[10], s1[11]);
            unsigned h0 = cvtpk(s1[12], s1[13]),h1 = cvtpk(s1[14], s1[15]);
            pswap(g0, h0); pswap(g1, h1);
            union { u32x4 u; s8v s; } pf0, pf1, pf2, pf3;
            pf0.u = (u32x4){a0, a1, b0, b1};
            pf1.u = (u32x4){c0, c1, d0, d1};
            pf2.u = (u32x4){e0, e1, f0, f1};
            pf3.u = (u32x4){g0, g1, h0, h1};

            // ---- O += P @ V (V^T-frags from LDS), 2 dh-halves x 4 key-chunks ----
            {
                s8v v00 = *(const s8v*)(vb_ + swz(q,    0*2+hi));
                s8v v01 = *(const s8v*)(vb_ + swz(q,    1*2+hi));
                s8v v02 = *(const s8v*)(vb_ + swz(q,    2*2+hi));
                s8v v03 = *(const s8v*)(vb_ + swz(q,    3*2+hi));
                s8v v10 = *(const s8v*)(vb_ + swz(32+q, 0*2+hi));
                s8v v11 = *(const s8v*)(vb_ + swz(32+q, 1*2+hi));
                s8v v12 = *(const s8v*)(vb_ + swz(32+q, 2*2+hi));
                s8v v13 = *(const s8v*)(vb_ + swz(32+q, 3*2+hi));
                __builtin_amdgcn_s_setprio(1);
                o0 = __builtin_amdgcn_mfma_f32_32x32x16_bf16(pf0.s, v00, o0, 0,0,0);
                o1 = __builtin_amdgcn_mfma_f32_32x32x16_bf16(pf0.s, v10, o1, 0,0,0);
                o0 = __builtin_amdgcn_mfma_f32_32x32x16_bf16(pf1.s, v01, o0, 0,0,0);
                o1 = __builtin_amdgcn_mfma_f32_32x32x16_bf16(pf1.s, v11, o1, 0,0,0);
                o0 = __builtin_amdgcn_mfma_f32_32x32x16_bf16(pf2.s, v02, o0, 0,0,0);
                o1 = __builtin_amdgcn_mfma_f32_32x32x16_bf16(pf2.s, v12, o1, 0,0,0);
                o0 = __builtin_amdgcn_mfma_f32_32x32x16_bf16(pf3.s, v03, o0, 0,0,0);
                o1 = __builtin_amdgcn_mfma_f32_32x32x16_bf16(pf3.s, v13, o1, 0,0,0);
                __builtin_amdgcn_s_setprio(0);
            }
            cur ^= 1;
        }

        float wl = wc * winv;
        #pragma unroll
        for (int r=0;r<16;++r){
            float lb = __shfl(l_i, ((r&3)+8*(r>>2)) + 4*hi, 64);
            float sc = wl / lb;
            aO0[r] += o0[r] * sc;
            aO1[r] += o1[r] * sc;
        }
    }

    #pragma unroll
    for (int r=0;r<16;++r){
        int qrow = ((r&3)+8*(r>>2)) + 4*hi;
        size_t row = (size_t)b*S_ + (size_t)qt*128 + wv*32 + qrow;
        accOut[row*D_ + h*DH_ + q]      = f2bf1(aO0[r]);
        accOut[row*D_ + h*DH_ + 32 + q] = f2bf1(aO1[r]);
    }
}

// ---------------- launch ----------------
extern "C" void kernel_launch(void* const* d_in, const int* in_sizes, int n_in,
                              void* d_out, int out_size, void* d_ws, size_t ws_size,
                              hipStream_t stream)
{
    const float* query = (const float*)d_in[0];
    const float* key   = (const float*)d_in[1];
    const float* value = (const float*)d_in[2];
    const float* Wq = (const float*)d_in[3];  const float* bq = (const float*)d_in[4];
    const float* Wk = (const float*)d_in[5];  const float* bk = (const float*)d_in[6];
    const float* Wv = (const float*)d_in[7];  const float* bv = (const float*)d_in[8];
    const float* Wo = (const float*)d_in[9];  const float* bo = (const float*)d_in[10];
    const float* wlv = (const float*)d_in[11];

    char* w = (char*)d_ws;
    unsigned short* qhb  = (unsigned short*)(w);             // 8 MB [B,H,S,DH]
    unsigned short* khb0 = (unsigned short*)(w + 8388608);   // 8 MB [B,H,S,DH]
    unsigned short* khb1 = (unsigned short*)(w + 16777216);  // 4 MB
    unsigned short* khb2 = (unsigned short*)(w + 20971520);  // 2 MB
    unsigned short* vtb0 = (unsigned short*)(w + 23068672);  // 8 MB [B,H,DH,S]
    unsigned short* vtb1 = (unsigned short*)(w + 31457280);  // 4 MB
    unsigned short* vtb2 = (unsigned short*)(w + 35651584);  // 2 MB
    unsigned short* accb = (unsigned short*)(w + 37748736);  // 8 MB [B,S,D]
    unsigned short* Wtq  = (unsigned short*)(w + 46137344);  // 2 MB each
    unsigned short* Wtk  = (unsigned short*)(w + 48234496);
    unsigned short* Wtv  = (unsigned short*)(w + 50331648);
    unsigned short* Wto  = (unsigned short*)(w + 52428800);  // end 54525952

    dim3 bb(256);
    wtrans<<<dim3(32,32,4), bb, 0, stream>>>(Wq, Wk, Wv, Wo, Wtq, Wtk, Wtv, Wto);

    const float scale_q = 0.125f * 1.44269504088896f;   // 1/sqrt(DH) * log2(e)
    dim3 gg(D_/128, (B_*S_)/128);
    gemm_mfma<1,1><<<gg, bb, 0, stream>>>(query, Wtq, bq, qhb,  scale_q);
    gemm_mfma<1,1><<<gg, bb, 0, stream>>>(key,   Wtk, bk, khb0, 1.0f);
    gemm_mfma<2,1><<<gg, bb, 0, stream>>>(value, Wtv, bv, vtb0, 1.0f);

    int n1 = B_ * H_ * (S_/2) * DH_ / 4;   // 524288
    int n2 = B_ * H_ * (S_/4) * DH_ / 4;   // 262144
    pool2_bf16<<<n1/256, bb, 0, stream>>>(khb0, khb1, n1, S_);
    pool2_bf16<<<n2/256, bb, 0, stream>>>(khb1, khb2, n2, S_/2);
    // V pools on transposed layout: shift = log2(Sout/4)
    pool2T<<<n1/256, bb, 0, stream>>>(vtb0, vtb1, n1, S_,   8);
    pool2T<<<n2/256, bb, 0, stream>>>(vtb1, vtb2, n2, S_/2, 7);

    attn_mfma5<<<B_*H_*(S_/128), bb, 0, stream>>>(qhb, khb0, khb1, khb2,
                                                  vtb0, vtb1, vtb2, wlv, accb);

    gemm_mfma<0,0><<<gg, bb, 0, stream>>>(accb, Wto, bo, d_out, 1.0f);
}